// Round 1
// baseline (11745.099 us; speedup 1.0000x reference)
//
#include <hip/hip_runtime.h>
#include <math.h>

#define BD 256

// ---------------- init: res = emb_cur = entity_emb ----------------
__global__ void k_init(const float4* __restrict__ ent, float4* __restrict__ emb,
                       float4* __restrict__ out, int n4) {
  int i = blockIdx.x * BD + threadIdx.x;
  if (i < n4) { float4 v = ent[i]; emb[i] = v; out[i] = v; }
}

// ---------------- Q = emb @ Wq  (thread per (node, j)) ----------------
__global__ void k_q(const float* __restrict__ emb, const float* __restrict__ Wq,
                    float* __restrict__ Q, int N) {
  int tid = threadIdx.x;
  int j = tid & 63;
  int n = blockIdx.x * 4 + (tid >> 6);
  if (n >= N) return;
  const float* er = emb + (size_t)n * 64;
  float acc = 0.f;
#pragma unroll
  for (int i = 0; i < 64; i++) acc = fmaf(er[i], Wq[i * 64 + j], acc);
  Q[(size_t)n * 64 + j] = acc;
}

// ---------------- per-edge attention logits + exp + segment-sum ----------------
__global__ void k_att(const float* __restrict__ emb, const float* __restrict__ Q,
                      const float* __restrict__ Wk, const float* __restrict__ weight,
                      const int* __restrict__ head, const int* __restrict__ tail,
                      const int* __restrict__ etype,
                      float* __restrict__ expatt, float* __restrict__ attnorm, int E) {
  int e = blockIdx.x * BD + threadIdx.x;
  if (e >= E) return;
  int hn = head[e], tn = tail[e], rt = etype[e] - 1;
  const float4* ev = (const float4*)(emb + (size_t)tn * 64);
  const float4* rv = (const float4*)(weight + (size_t)rt * 64);
  float K[64];
#pragma unroll
  for (int j = 0; j < 64; j++) K[j] = 0.f;
#pragma unroll 2
  for (int i4 = 0; i4 < 16; i4++) {
    float4 ee = ev[i4]; float4 rr = rv[i4];
    float x0 = ee.x * rr.x, x1 = ee.y * rr.y, x2 = ee.z * rr.z, x3 = ee.w * rr.w;
    const float* w0 = Wk + (i4 * 4 + 0) * 64;
    const float* w1 = Wk + (i4 * 4 + 1) * 64;
    const float* w2 = Wk + (i4 * 4 + 2) * 64;
    const float* w3 = Wk + (i4 * 4 + 3) * 64;
#pragma unroll
    for (int j = 0; j < 64; j++)
      K[j] = fmaf(x3, w3[j], fmaf(x2, w2[j], fmaf(x1, w1[j], fmaf(x0, w0[j], K[j]))));
  }
  const float4* qv = (const float4*)(Q + (size_t)hn * 64);
#pragma unroll
  for (int h = 0; h < 4; h++) {
    float ah = 0.f;
#pragma unroll
    for (int jj = 0; jj < 4; jj++) {
      float4 qq = qv[h * 4 + jj];
      int b = h * 16 + jj * 4;
      ah += qq.x * K[b] + qq.y * K[b + 1] + qq.z * K[b + 2] + qq.w * K[b + 3];
    }
    ah = fminf(10.f, fmaxf(-10.f, ah));
    float ea = expf(ah);
    expatt[(size_t)e * 4 + h] = ea;
    atomicAdd(attnorm + (size_t)hn * 4 + h, ea);
  }
}

// ---------------- per-edge V matvec + weighted scatter into kg ----------------
__global__ void k_v(const float* __restrict__ emb, const float* __restrict__ Wv,
                    const float* __restrict__ weight,
                    const int* __restrict__ head, const int* __restrict__ tail,
                    const int* __restrict__ etype,
                    const float* __restrict__ expatt, const float* __restrict__ attnorm,
                    float* __restrict__ kg, int E) {
  int e = blockIdx.x * BD + threadIdx.x;
  if (e >= E) return;
  int hn = head[e], tn = tail[e], rt = etype[e] - 1;
  const float4* ev = (const float4*)(emb + (size_t)tn * 64);
  const float4* rv = (const float4*)(weight + (size_t)rt * 64);
  float V[64];
#pragma unroll
  for (int j = 0; j < 64; j++) V[j] = 0.f;
#pragma unroll 2
  for (int i4 = 0; i4 < 16; i4++) {
    float4 ee = ev[i4]; float4 rr = rv[i4];
    float x0 = ee.x * rr.x, x1 = ee.y * rr.y, x2 = ee.z * rr.z, x3 = ee.w * rr.w;
    const float* w0 = Wv + (i4 * 4 + 0) * 64;
    const float* w1 = Wv + (i4 * 4 + 1) * 64;
    const float* w2 = Wv + (i4 * 4 + 2) * 64;
    const float* w3 = Wv + (i4 * 4 + 3) * 64;
#pragma unroll
    for (int j = 0; j < 64; j++)
      V[j] = fmaf(x3, w3[j], fmaf(x2, w2[j], fmaf(x1, w1[j], fmaf(x0, w0[j], V[j]))));
  }
  float a[4];
#pragma unroll
  for (int h = 0; h < 4; h++)
    a[h] = expatt[(size_t)e * 4 + h] / (attnorm[(size_t)hn * 4 + h] + 1e-8f);
  float* kr = kg + (size_t)hn * 64;
#pragma unroll
  for (int h = 0; h < 4; h++) {
#pragma unroll
    for (int j2 = 0; j2 < 16; j2++)
      atomicAdd(kr + h * 16 + j2, a[h] * V[h * 16 + j2]);
  }
}

// ---------------- per-edge similarity w + segment max (float-as-uint, w>=0) ----------------
__global__ void k_sim(const float* __restrict__ kg, const float* __restrict__ weight,
                      const int* __restrict__ head, const int* __restrict__ tail,
                      const int* __restrict__ etype,
                      float* __restrict__ wbuf, unsigned int* __restrict__ m, int E) {
  int e = blockIdx.x * BD + threadIdx.x;
  if (e >= E) return;
  int hn = head[e], tn = tail[e], rt = etype[e] - 1;
  const float4* kh = (const float4*)(kg + (size_t)hn * 64);
  const float4* kt = (const float4*)(kg + (size_t)tn * 64);
  const float4* rv = (const float4*)(weight + (size_t)rt * 64);
  float sh = 0.f, st = 0.f;
#pragma unroll
  for (int i = 0; i < 16; i++) {
    float4 r = rv[i]; float4 a = kh[i]; float4 b = kt[i];
    float p;
    p = a.x * r.x; sh = fmaf(p, p, sh);
    p = a.y * r.y; sh = fmaf(p, p, sh);
    p = a.z * r.z; sh = fmaf(p, p, sh);
    p = a.w * r.w; sh = fmaf(p, p, sh);
    p = b.x * r.x; st = fmaf(p, p, st);
    p = b.y * r.y; st = fmaf(p, p, st);
    p = b.z * r.z; st = fmaf(p, p, st);
    p = b.w * r.w; st = fmaf(p, p, st);
  }
  float wv = sh * st;   // (hn*tn)^2 == sumsq_h * sumsq_t  (no sqrt needed)
  wbuf[e] = wv;
  atomicMax(m + hn, __float_as_uint(wv));
}

// ---------------- exp(w - m[head]) + segment sum ----------------
__global__ void k_exps(const int* __restrict__ head, const unsigned int* __restrict__ m,
                       float* __restrict__ wbuf, float* __restrict__ s, int E) {
  int e = blockIdx.x * BD + threadIdx.x;
  if (e >= E) return;
  int hn = head[e];
  float mv = __uint_as_float(m[hn]);
  float ew = expf(wbuf[e] - mv);
  wbuf[e] = ew;
  atomicAdd(s + hn, ew);
}

// ---------------- weighted aggregation of emb[tail] into agg[head] ----------------
__global__ void k_agg(const float* __restrict__ emb,
                      const int* __restrict__ head, const int* __restrict__ tail,
                      const float* __restrict__ wbuf, const float* __restrict__ s,
                      float* __restrict__ agg, int E) {
  int e = blockIdx.x * BD + threadIdx.x;
  if (e >= E) return;
  int hn = head[e], tn = tail[e];
  float a = wbuf[e] / (s[hn] + 1e-16f);
  const float4* ev = (const float4*)(emb + (size_t)tn * 64);
  float* ar = agg + (size_t)hn * 64;
#pragma unroll
  for (int i = 0; i < 16; i++) {
    float4 v = ev[i];
    atomicAdd(ar + i * 4 + 0, a * v.x);
    atomicAdd(ar + i * 4 + 1, a * v.y);
    atomicAdd(ar + i * 4 + 2, a * v.z);
    atomicAdd(ar + i * 4 + 3, a * v.w);
  }
}

// ---------------- row-normalize agg -> emb_cur, accumulate into out ----------------
__global__ void k_norm(const float* __restrict__ agg, float* __restrict__ emb,
                       float* __restrict__ out, int N) {
  int tid = threadIdx.x;
  int j = tid & 63;
  int n = blockIdx.x * 4 + (tid >> 6);
  if (n >= N) return;
  float v = agg[(size_t)n * 64 + j];
  float ss = v * v;
#pragma unroll
  for (int o = 32; o >= 1; o >>= 1) ss += __shfl_xor(ss, o, 64);
  float nr = fmaxf(sqrtf(ss), 1e-12f);
  float en = v / nr;
  emb[(size_t)n * 64 + j] = en;
  out[(size_t)n * 64 + j] += en;
}

extern "C" void kernel_launch(void* const* d_in, const int* in_sizes, int n_in,
                              void* d_out, int out_size, void* d_ws, size_t ws_size,
                              hipStream_t stream) {
  const float* ent    = (const float*)d_in[0];
  const float* weight = (const float*)d_in[1];
  const float* Wq     = (const float*)d_in[2];
  const float* Wk     = (const float*)d_in[3];
  const float* Wv     = (const float*)d_in[4];
  const int*   eidx   = (const int*)d_in[5];
  const int*   etype  = (const int*)d_in[6];
  int N = in_sizes[0] / 64;
  int E = in_sizes[6];
  const int* head = eidx;
  const int* tail = eidx + E;

  float* ws      = (float*)d_ws;
  float* emb     = ws;                          // N*64  current embedding
  float* qagg    = emb + (size_t)N * 64;        // N*64  Q, later reused as agg
  float* expatt  = qagg + (size_t)N * 64;       // E*4   exp(att); first E floats reused as wbuf
  float* wbuf    = expatt;
  float* kg      = expatt + (size_t)E * 4;      // N*64  kg_emb   --- zero region start
  float* attnorm = kg + (size_t)N * 64;         // N*4
  float* mbuf    = attnorm + (size_t)N * 4;     // N     (uint bits)
  float* sbuf    = mbuf + N;                    // N

  int n4   = N * 64 / 4;
  int bl4  = (n4 + BD - 1) / BD;
  int ebl  = (E + BD - 1) / BD;
  int nbl  = (N + 3) / 4;

  k_init<<<bl4, BD, 0, stream>>>((const float4*)ent, (float4*)emb, (float4*)d_out, n4);

  for (int l = 0; l < 2; l++) {
    const float* wq = Wq + (size_t)l * 64 * 64;
    const float* wk = Wk + (size_t)l * 64 * 64;
    const float* wv = Wv + (size_t)l * 64 * 64;

    // zero kg + attnorm + m + s (contiguous N*70 floats)
    hipMemsetAsync(kg, 0, (size_t)N * 70 * sizeof(float), stream);

    k_q  <<<nbl, BD, 0, stream>>>(emb, wq, qagg, N);
    k_att<<<ebl, BD, 0, stream>>>(emb, qagg, wk, weight, head, tail, etype,
                                  expatt, attnorm, E);
    // qagg done serving as Q; zero it to serve as agg
    hipMemsetAsync(qagg, 0, (size_t)N * 64 * sizeof(float), stream);

    k_v  <<<ebl, BD, 0, stream>>>(emb, wv, weight, head, tail, etype,
                                  expatt, attnorm, kg, E);
    k_sim<<<ebl, BD, 0, stream>>>(kg, weight, head, tail, etype,
                                  wbuf, (unsigned int*)mbuf, E);
    k_exps<<<ebl, BD, 0, stream>>>(head, (const unsigned int*)mbuf, wbuf, sbuf, E);
    k_agg<<<ebl, BD, 0, stream>>>(emb, head, tail, wbuf, sbuf, qagg, E);
    k_norm<<<nbl, BD, 0, stream>>>(qagg, emb, (float*)d_out, N);
  }
}

// Round 2
// 1425.035 us; speedup vs baseline: 8.2420x; 8.2420x over previous
//
#include <hip/hip_runtime.h>
#include <math.h>

#define BD 256

// ---------------- init: res = emb_cur = entity_emb ----------------
__global__ void k_init(const float4* __restrict__ ent, float4* __restrict__ emb,
                       float4* __restrict__ out, int n4) {
  int i = blockIdx.x * BD + threadIdx.x;
  if (i < n4) { float4 v = ent[i]; emb[i] = v; out[i] = v; }
}

// ---------------- CSR build ----------------
__global__ void k_deg(const int* __restrict__ head, int* __restrict__ deg, int E) {
  int e = blockIdx.x * BD + threadIdx.x;
  if (e < E) atomicAdd(&deg[head[e]], 1);
}

__global__ void k_scan_a(const int* __restrict__ deg, int* __restrict__ rowptr,
                         int* __restrict__ bsum, int N) {
  __shared__ int s[BD];
  int t = threadIdx.x, i = blockIdx.x * BD + t;
  int v = (i < N) ? deg[i] : 0;
  s[t] = v; __syncthreads();
  for (int off = 1; off < BD; off <<= 1) {
    int add = (t >= off) ? s[t - off] : 0;
    __syncthreads();
    s[t] += add;
    __syncthreads();
  }
  if (i < N) rowptr[i] = s[t] - v;           // exclusive within block
  if (t == BD - 1) bsum[blockIdx.x] = s[t];
}

__global__ void k_scan_b(const int* __restrict__ bsum, int* __restrict__ boff, int nb) {
  __shared__ int s[512];
  int t = threadIdx.x;
  int v = (t < nb) ? bsum[t] : 0;
  s[t] = v; __syncthreads();
  for (int off = 1; off < 512; off <<= 1) {
    int add = (t >= off) ? s[t - off] : 0;
    __syncthreads();
    s[t] += add;
    __syncthreads();
  }
  boff[t] = s[t] - v;                        // exclusive block offsets
}

__global__ void k_scan_c(int* __restrict__ rowptr, const int* __restrict__ boff,
                         int N, int E) {
  int i = blockIdx.x * BD + threadIdx.x;
  if (i < N) rowptr[i] += boff[blockIdx.x];
  if (i == 0) rowptr[N] = E;
}

__global__ void k_curinit(const int* __restrict__ rowptr, int* __restrict__ cur, int N) {
  int i = blockIdx.x * BD + threadIdx.x;
  if (i < N) cur[i] = rowptr[i];
}

__global__ void k_scatter(const int* __restrict__ head, int* __restrict__ cur,
                          int* __restrict__ csr, int E) {
  int e = blockIdx.x * BD + threadIdx.x;
  if (e < E) { int p = atomicAdd(&cur[head[e]], 1); csr[p] = e; }
}

// ---------------- Q = emb @ Wq  (thread per (node, j)) ----------------
__global__ void k_q(const float* __restrict__ emb, const float* __restrict__ Wq,
                    float* __restrict__ Q, int N) {
  int tid = threadIdx.x;
  int j = tid & 63;
  int n = blockIdx.x * 4 + (tid >> 6);
  if (n >= N) return;
  const float* er = emb + (size_t)n * 64;
  float acc = 0.f;
#pragma unroll
  for (int i = 0; i < 64; i++) acc = fmaf(er[i], Wq[i * 64 + j], acc);
  Q[(size_t)n * 64 + j] = acc;
}

// ---------------- per-edge attention logits -> expatt (no atomics) ----------------
__global__ void k_att(const float* __restrict__ emb, const float* __restrict__ Q,
                      const float* __restrict__ Wk, const float* __restrict__ weight,
                      const int* __restrict__ head, const int* __restrict__ tail,
                      const int* __restrict__ etype,
                      float4* __restrict__ expatt, int E) {
  int e = blockIdx.x * BD + threadIdx.x;
  if (e >= E) return;
  int hn = head[e], tn = tail[e], rt = etype[e] - 1;
  const float4* ev = (const float4*)(emb + (size_t)tn * 64);
  const float4* rv = (const float4*)(weight + (size_t)rt * 64);
  float K[64];
#pragma unroll
  for (int j = 0; j < 64; j++) K[j] = 0.f;
#pragma unroll 2
  for (int i4 = 0; i4 < 16; i4++) {
    float4 ee = ev[i4]; float4 rr = rv[i4];
    float x0 = ee.x * rr.x, x1 = ee.y * rr.y, x2 = ee.z * rr.z, x3 = ee.w * rr.w;
    const float* w0 = Wk + (i4 * 4 + 0) * 64;
    const float* w1 = Wk + (i4 * 4 + 1) * 64;
    const float* w2 = Wk + (i4 * 4 + 2) * 64;
    const float* w3 = Wk + (i4 * 4 + 3) * 64;
#pragma unroll
    for (int j = 0; j < 64; j++)
      K[j] = fmaf(x3, w3[j], fmaf(x2, w2[j], fmaf(x1, w1[j], fmaf(x0, w0[j], K[j]))));
  }
  const float4* qv = (const float4*)(Q + (size_t)hn * 64);
  float ea[4];
#pragma unroll
  for (int h = 0; h < 4; h++) {
    float ah = 0.f;
#pragma unroll
    for (int jj = 0; jj < 4; jj++) {
      float4 qq = qv[h * 4 + jj];
      int b = h * 16 + jj * 4;
      ah += qq.x * K[b] + qq.y * K[b + 1] + qq.z * K[b + 2] + qq.w * K[b + 3];
    }
    ah = fminf(10.f, fmaxf(-10.f, ah));
    ea[h] = expf(ah);
  }
  expatt[e] = make_float4(ea[0], ea[1], ea[2], ea[3]);
}

// ---------------- node pass: attnorm + S accumulation + S@Wv -> kg ----------------
// wave per node; lane i holds S[h][i] for h=0..3
__global__ void k_s(const float* __restrict__ emb, const float* __restrict__ weight,
                    const float* __restrict__ Wv, const float4* __restrict__ expatt,
                    const int* __restrict__ tail, const int* __restrict__ etype,
                    const int* __restrict__ rowptr, const int* __restrict__ csr,
                    float* __restrict__ kg, int N) {
  __shared__ float lds[4 * 256];
  int t = threadIdx.x, lane = t & 63, w = t >> 6;
  int n = blockIdx.x * 4 + w;
  if (n >= N) return;                    // wave-local LDS use only: no block barrier needed
  int base = rowptr[n], deg = rowptr[n + 1] - base;

  // segment-sum of exp(att) per head (lane-strided + shuffle reduce)
  float n0 = 0.f, n1 = 0.f, n2 = 0.f, n3 = 0.f;
  for (int k = lane; k < deg; k += 64) {
    float4 ea = expatt[csr[base + k]];
    n0 += ea.x; n1 += ea.y; n2 += ea.z; n3 += ea.w;
  }
#pragma unroll
  for (int off = 32; off >= 1; off >>= 1) {
    n0 += __shfl_xor(n0, off, 64); n1 += __shfl_xor(n1, off, 64);
    n2 += __shfl_xor(n2, off, 64); n3 += __shfl_xor(n3, off, 64);
  }
  float i0 = 1.f / (n0 + 1e-8f), i1 = 1.f / (n1 + 1e-8f);
  float i2 = 1.f / (n2 + 1e-8f), i3 = 1.f / (n3 + 1e-8f);

  // S[h][lane] = sum_e a_eh * x_e[lane],  x = emb[tail] * rel
  float S0 = 0.f, S1 = 0.f, S2 = 0.f, S3 = 0.f;
  for (int k = 0; k < deg; k++) {
    int e = csr[base + k];
    int tn = tail[e], rt = etype[e] - 1;
    float x = emb[(size_t)tn * 64 + lane] * weight[rt * 64 + lane];
    float4 ea = expatt[e];
    S0 = fmaf(ea.x * i0, x, S0);
    S1 = fmaf(ea.y * i1, x, S1);
    S2 = fmaf(ea.z * i2, x, S2);
    S3 = fmaf(ea.w * i3, x, S3);
  }

  // kg[n][j] = sum_i S[j>>4][i] * Wv[i][j]   (wave-local LDS transpose)
  float* L = lds + w * 256;
  L[lane] = S0; L[64 + lane] = S1; L[128 + lane] = S2; L[192 + lane] = S3;
  const float* Lh = L + (lane >> 4) * 64;
  float acc = 0.f;
#pragma unroll
  for (int i = 0; i < 64; i++) acc = fmaf(Lh[i], Wv[i * 64 + lane], acc);
  kg[(size_t)n * 64 + lane] = acc;
}

// ---------------- D[n][r] = sum_j (kg[n][j]*rel[r][j])^2  (31 relations) ----------------
__global__ void k_d(const float* __restrict__ kg, const float* __restrict__ weight,
                    float* __restrict__ D, int N) {
  int t = threadIdx.x;
  int r = t & 31;
  int n = blockIdx.x * 8 + (t >> 5);
  if (n >= N) return;
  if (r >= 31) { D[(size_t)n * 32 + r] = 0.f; return; }
  const float* kr = kg + (size_t)n * 64;
  const float* wr = weight + (size_t)r * 64;
  float acc = 0.f;
#pragma unroll
  for (int j = 0; j < 64; j++) { float p = kr[j] * wr[j]; acc = fmaf(p, p, acc); }
  D[(size_t)n * 32 + r] = acc;
}

// ---------------- node pass: scatter-softmax + aggregation + normalize + residual ----------------
__global__ void k_aggnorm(const float* __restrict__ emb, const float* __restrict__ D,
                          const int* __restrict__ tail, const int* __restrict__ etype,
                          const int* __restrict__ rowptr, const int* __restrict__ csr,
                          float* __restrict__ embn, float* __restrict__ out, int N) {
  int t = threadIdx.x, lane = t & 63;
  int n = blockIdx.x * 4 + (t >> 6);
  if (n >= N) return;
  int base = rowptr[n], deg = rowptr[n + 1] - base;
  float agg = 0.f;
  if (deg > 0) {
    const float* Dn = D + (size_t)n * 32;
    float m = -1e30f;
    for (int k = lane; k < deg; k += 64) {
      int e = csr[base + k]; int rt = etype[e] - 1;
      float wv = Dn[rt] * D[(size_t)tail[e] * 32 + rt];
      m = fmaxf(m, wv);
    }
#pragma unroll
    for (int off = 32; off >= 1; off >>= 1) m = fmaxf(m, __shfl_xor(m, off, 64));
    float s = 0.f;
    for (int k = lane; k < deg; k += 64) {
      int e = csr[base + k]; int rt = etype[e] - 1;
      float wv = Dn[rt] * D[(size_t)tail[e] * 32 + rt];
      s += expf(wv - m);
    }
#pragma unroll
    for (int off = 32; off >= 1; off >>= 1) s += __shfl_xor(s, off, 64);
    float inv = 1.f / (s + 1e-16f);
    for (int k = 0; k < deg; k++) {
      int e = csr[base + k];
      int tn = tail[e], rt = etype[e] - 1;
      float wv = Dn[rt] * D[(size_t)tn * 32 + rt];
      float a = expf(wv - m) * inv;
      agg = fmaf(a, emb[(size_t)tn * 64 + lane], agg);
    }
  }
  float ss = agg * agg;
#pragma unroll
  for (int off = 32; off >= 1; off >>= 1) ss += __shfl_xor(ss, off, 64);
  float nr = fmaxf(sqrtf(ss), 1e-12f);
  float en = agg / nr;
  embn[(size_t)n * 64 + lane] = en;
  out[(size_t)n * 64 + lane] += en;
}

extern "C" void kernel_launch(void* const* d_in, const int* in_sizes, int n_in,
                              void* d_out, int out_size, void* d_ws, size_t ws_size,
                              hipStream_t stream) {
  const float* ent    = (const float*)d_in[0];
  const float* weight = (const float*)d_in[1];
  const float* Wq     = (const float*)d_in[2];
  const float* Wk     = (const float*)d_in[3];
  const float* Wv     = (const float*)d_in[4];
  const int*   eidx   = (const int*)d_in[5];
  const int*   etype  = (const int*)d_in[6];
  int N = in_sizes[0] / 64;
  int E = in_sizes[6];
  const int* head = eidx;
  const int* tail = eidx + E;

  // workspace layout (floats)
  float* ws   = (float*)d_ws;
  size_t o = 0;
  float* embA = ws + o; o += (size_t)N * 64;
  float* embB = ws + o; o += (size_t)N * 64;
  size_t edsz = (size_t)E * 4 > (size_t)N * 32 ? (size_t)E * 4 : (size_t)N * 32;
  float* ed   = ws + o; o += edsz;              // expatt (E*4) then D (N*32)
  int* rowptr = (int*)(ws + o); o += N + 1;
  int* csr    = (int*)(ws + o); o += E;
  int* deg    = (int*)(ws + o); o += N;
  int* cur    = (int*)(ws + o); o += N;
  int* bsum   = (int*)(ws + o); o += 512;
  int* boff   = (int*)(ws + o); o += 512;

  int n4  = N * 64 / 4;
  int bl4 = (n4 + BD - 1) / BD;
  int ebl = (E + BD - 1) / BD;
  int nbl = (N + 3) / 4;       // wave-per-node kernels (4 waves/block)
  int sbl = (N + BD - 1) / BD; // scan decomposition (1 elem/thread)

  k_init<<<bl4, BD, 0, stream>>>((const float4*)ent, (float4*)embA, (float4*)d_out, n4);

  // ---- CSR by head (once; edge_index constant across layers) ----
  hipMemsetAsync(deg, 0, (size_t)N * sizeof(int), stream);
  k_deg    <<<ebl, BD, 0, stream>>>(head, deg, E);
  k_scan_a <<<sbl, BD, 0, stream>>>(deg, rowptr, bsum, N);
  k_scan_b <<<1, 512, 0, stream>>>(bsum, boff, sbl);
  k_scan_c <<<sbl, BD, 0, stream>>>(rowptr, boff, N, E);
  k_curinit<<<sbl, BD, 0, stream>>>(rowptr, cur, N);
  k_scatter<<<ebl, BD, 0, stream>>>(head, cur, csr, E);

  float* emb = embA;
  float* alt = embB;
  for (int l = 0; l < 2; l++) {
    const float* wq = Wq + (size_t)l * 64 * 64;
    const float* wk = Wk + (size_t)l * 64 * 64;
    const float* wv = Wv + (size_t)l * 64 * 64;

    k_q  <<<nbl, BD, 0, stream>>>(emb, wq, alt, N);                       // alt = Q
    k_att<<<ebl, BD, 0, stream>>>(emb, alt, wk, weight, head, tail, etype,
                                  (float4*)ed, E);                         // ed = expatt
    k_s  <<<nbl, BD, 0, stream>>>(emb, weight, wv, (const float4*)ed,
                                  tail, etype, rowptr, csr, alt, N);       // alt = kg
    k_d  <<<(N + 7) / 8, BD, 0, stream>>>(alt, weight, ed, N);             // ed = D
    k_aggnorm<<<nbl, BD, 0, stream>>>(emb, ed, tail, etype, rowptr, csr,
                                      alt, (float*)d_out, N);              // alt = new emb
    float* tmp = emb; emb = alt; alt = tmp;
  }
}

// Round 3
// 1207.704 us; speedup vs baseline: 9.7251x; 1.1800x over previous
//
#include <hip/hip_runtime.h>
#include <math.h>

#define BD 256
#define CAP 192

// ---------------- init: res = emb_cur = entity_emb ----------------
__global__ void k_init(const float4* __restrict__ ent, float4* __restrict__ emb,
                       float4* __restrict__ out, int n4) {
  int i = blockIdx.x * BD + threadIdx.x;
  if (i < n4) { float4 v = ent[i]; emb[i] = v; out[i] = v; }
}

// ---------------- CSR build ----------------
__global__ void k_deg(const int* __restrict__ head, int* __restrict__ deg, int E) {
  int e = blockIdx.x * BD + threadIdx.x;
  if (e < E) atomicAdd(&deg[head[e]], 1);
}

__global__ void k_scan_a(const int* __restrict__ deg, int* __restrict__ rowptr,
                         int* __restrict__ bsum, int N) {
  __shared__ int s[BD];
  int t = threadIdx.x, i = blockIdx.x * BD + t;
  int v = (i < N) ? deg[i] : 0;
  s[t] = v; __syncthreads();
  for (int off = 1; off < BD; off <<= 1) {
    int add = (t >= off) ? s[t - off] : 0;
    __syncthreads();
    s[t] += add;
    __syncthreads();
  }
  if (i < N) rowptr[i] = s[t] - v;
  if (t == BD - 1) bsum[blockIdx.x] = s[t];
}

__global__ void k_scan_b(const int* __restrict__ bsum, int* __restrict__ boff, int nb) {
  __shared__ int s[512];
  int t = threadIdx.x;
  int v = (t < nb) ? bsum[t] : 0;
  s[t] = v; __syncthreads();
  for (int off = 1; off < 512; off <<= 1) {
    int add = (t >= off) ? s[t - off] : 0;
    __syncthreads();
    s[t] += add;
    __syncthreads();
  }
  boff[t] = s[t] - v;
}

__global__ void k_scan_c(int* __restrict__ rowptr, const int* __restrict__ boff,
                         int N, int E) {
  int i = blockIdx.x * BD + threadIdx.x;
  if (i < N) rowptr[i] += boff[blockIdx.x];
  if (i == 0) rowptr[N] = E;
}

__global__ void k_curinit(const int* __restrict__ rowptr, int* __restrict__ cur, int N) {
  int i = blockIdx.x * BD + threadIdx.x;
  if (i < N) cur[i] = rowptr[i];
}

__global__ void k_scatter(const int* __restrict__ head, const int* __restrict__ tail,
                          const int* __restrict__ etype,
                          int* __restrict__ cur, int2* __restrict__ epack, int E) {
  int e = blockIdx.x * BD + threadIdx.x;
  if (e < E) {
    int p = atomicAdd(&cur[head[e]], 1);
    epack[p] = make_int2(tail[e], etype[e] - 1);
  }
}

// ---------------- M_h = Wq_h @ Wk_h^T : Mf[m][i*4+h] ----------------
__global__ void k_m(const float* __restrict__ Wq, const float* __restrict__ Wk,
                    float* __restrict__ Mf) {
  int tid = blockIdx.x * BD + threadIdx.x;   // 0..16383
  int c = tid & 255;                         // i*4+h
  int m = tid >> 8;
  int i = c >> 2, h = c & 3;
  const float* wq = Wq + m * 64 + h * 16;
  const float* wk = Wk + i * 64 + h * 16;
  float acc = 0.f;
#pragma unroll
  for (int d = 0; d < 16; d++) acc = fmaf(wq[d], wk[d], acc);
  Mf[tid] = acc;
}

// ---------------- G = emb @ Mf  (LDS-tiled, 64 nodes/block) ----------------
__global__ __launch_bounds__(256) void k_g(const float* __restrict__ emb,
                                           const float* __restrict__ Mf,
                                           float4* __restrict__ G4, int n0, int n1) {
  __shared__ float lM[64 * 256];             // 64 KB
  int t = threadIdx.x;
  const float4* Mf4 = (const float4*)Mf;
  float4* lM4 = (float4*)lM;
  for (int i = t; i < 4096; i += BD) lM4[i] = Mf4[i];
  __syncthreads();
  int lane = t & 63, w = t >> 6;
  int nloc0 = blockIdx.x * 64 + w * 16;
#pragma unroll
  for (int b = 0; b < 2; b++) {
    int nl = nloc0 + b * 8;
    float4 acc[8];
#pragma unroll
    for (int ni = 0; ni < 8; ni++) acc[ni] = make_float4(0.f, 0.f, 0.f, 0.f);
#pragma unroll 8
    for (int m = 0; m < 64; m++) {
      float4 Mv = lM4[m * 64 + lane];
#pragma unroll
      for (int ni = 0; ni < 8; ni++) {
        float em = emb[(size_t)(n0 + nl + ni) * 64 + m];   // reads beyond n1 stay in ws
        acc[ni].x = fmaf(em, Mv.x, acc[ni].x);
        acc[ni].y = fmaf(em, Mv.y, acc[ni].y);
        acc[ni].z = fmaf(em, Mv.z, acc[ni].z);
        acc[ni].w = fmaf(em, Mv.w, acc[ni].w);
      }
    }
#pragma unroll
    for (int ni = 0; ni < 8; ni++)
      if (n0 + nl + ni < n1) G4[(size_t)(nl + ni) * 64 + lane] = acc[ni];
  }
}

// ---------------- fused: att + softmax-denominator + S + S@Wv -> kg ----------------
__global__ void k_fused(const float* __restrict__ emb, const float* __restrict__ weight,
                        const float4* __restrict__ G4, const float* __restrict__ Wv,
                        const int2* __restrict__ epack, const int* __restrict__ rowptr,
                        float* __restrict__ kg, int n0, int n1) {
  __shared__ float lds[4 * 256];
  int t = threadIdx.x, lane = t & 63, w = t >> 6;
  int n = n0 + blockIdx.x * 4 + w;
  if (n >= n1) return;
  float4 Gv = G4[(size_t)(n - n0) * 64 + lane];
  int base = rowptr[n], deg = rowptr[n + 1] - base;
  float den0 = 0.f, den1 = 0.f, den2 = 0.f, den3 = 0.f;
  float S0 = 0.f, S1 = 0.f, S2 = 0.f, S3 = 0.f;
  if (deg > 0) {
    int2 p0 = epack[base];
    int2 p1 = (deg > 1) ? epack[base + 1] : p0;
    float x0 = emb[(size_t)p0.x * 64 + lane] * weight[(size_t)p0.y * 64 + lane];
    for (int k = 0; k < deg; k++) {
      int2 p2 = (k + 2 < deg) ? epack[base + k + 2] : p1;
      float x1 = (k + 1 < deg)
                   ? emb[(size_t)p1.x * 64 + lane] * weight[(size_t)p1.y * 64 + lane]
                   : 0.f;
      float a0 = x0 * Gv.x, a1 = x0 * Gv.y, a2 = x0 * Gv.z, a3 = x0 * Gv.w;
#pragma unroll
      for (int off = 32; off >= 1; off >>= 1) {
        a0 += __shfl_xor(a0, off, 64);
        a1 += __shfl_xor(a1, off, 64);
        a2 += __shfl_xor(a2, off, 64);
        a3 += __shfl_xor(a3, off, 64);
      }
      a0 = fminf(10.f, fmaxf(-10.f, a0));
      a1 = fminf(10.f, fmaxf(-10.f, a1));
      a2 = fminf(10.f, fmaxf(-10.f, a2));
      a3 = fminf(10.f, fmaxf(-10.f, a3));
      float e0 = __expf(a0), e1 = __expf(a1), e2 = __expf(a2), e3 = __expf(a3);
      den0 += e0; den1 += e1; den2 += e2; den3 += e3;
      S0 = fmaf(e0, x0, S0);
      S1 = fmaf(e1, x0, S1);
      S2 = fmaf(e2, x0, S2);
      S3 = fmaf(e3, x0, S3);
      x0 = x1; p1 = p2;
    }
  }
  S0 /= (den0 + 1e-8f);
  S1 /= (den1 + 1e-8f);
  S2 /= (den2 + 1e-8f);
  S3 /= (den3 + 1e-8f);
  // kg[n][j] = sum_i S[j>>4][i] * Wv[i][j]  (wave-local LDS, rotated to kill conflicts)
  float* L = lds + w * 256;
  L[lane] = S0; L[64 + lane] = S1; L[128 + lane] = S2; L[192 + lane] = S3;
  int h = lane >> 4;
  const float* Lh = L + h * 64;
  float acc = 0.f;
#pragma unroll
  for (int i = 0; i < 64; i++) {
    int ip = (i + h * 8) & 63;
    acc = fmaf(Lh[ip], Wv[ip * 64 + lane], acc);
  }
  kg[(size_t)n * 64 + lane] = acc;
}

// ---------------- D[n][r] = sum_j (kg[n][j]*rel[r][j])^2 ----------------
__global__ void k_d(const float* __restrict__ kg, const float* __restrict__ weight,
                    float* __restrict__ D, int N) {
  int t = threadIdx.x;
  int r = t & 31;
  int n = blockIdx.x * 8 + (t >> 5);
  if (n >= N) return;
  if (r >= 31) { D[(size_t)n * 32 + r] = 0.f; return; }
  const float* kr = kg + (size_t)n * 64;
  const float* wr = weight + (size_t)r * 64;
  float acc = 0.f;
#pragma unroll
  for (int j = 0; j < 64; j++) { float p = kr[j] * wr[j]; acc = fmaf(p, p, acc); }
  D[(size_t)n * 32 + r] = acc;
}

// ---------------- scatter-softmax + aggregation + normalize + residual ----------------
__global__ void k_aggnorm(const float* __restrict__ emb, const float* __restrict__ D,
                          const int2* __restrict__ epack, const int* __restrict__ rowptr,
                          float* __restrict__ embn, float* __restrict__ out, int N) {
  __shared__ float wls[4 * CAP];
  int t = threadIdx.x, lane = t & 63, w = t >> 6;
  int n = blockIdx.x * 4 + w;
  if (n >= N) return;
  int base = rowptr[n], deg = rowptr[n + 1] - base;
  float agg = 0.f;
  if (deg > 0) {
    const float* Dn = D + (size_t)n * 32;
    float* wl = wls + w * CAP;
    float m = -1e30f, s = 0.f;
    for (int k = lane; k < deg; k += 64) {
      int2 p = epack[base + k];
      float wv = Dn[p.y] * D[(size_t)p.x * 32 + p.y];
      if (k < CAP) wl[k] = wv;
      float mn = fmaxf(m, wv);
      s = s * __expf(m - mn) + __expf(wv - mn);
      m = mn;
    }
#pragma unroll
    for (int off = 32; off >= 1; off >>= 1) {
      float mo = __shfl_xor(m, off, 64);
      float so = __shfl_xor(s, off, 64);
      float mn = fmaxf(m, mo);
      s = s * __expf(m - mn) + so * __expf(mo - mn);
      m = mn;
    }
    float inv = 1.f / (s + 1e-16f);
    int2 p0 = epack[base];
    int2 p1 = (deg > 1) ? epack[base + 1] : p0;
    float xa0 = emb[(size_t)p0.x * 64 + lane];
    for (int k = 0; k < deg; k++) {
      int2 p2 = (k + 2 < deg) ? epack[base + k + 2] : p1;
      float xa1 = (k + 1 < deg) ? emb[(size_t)p1.x * 64 + lane] : 0.f;
      float wv = (k < CAP) ? wl[k] : Dn[p0.y] * D[(size_t)p0.x * 32 + p0.y];
      float a = __expf(wv - m) * inv;
      agg = fmaf(a, xa0, agg);
      xa0 = xa1; p0 = p1; p1 = p2;
    }
  }
  float ss = agg * agg;
#pragma unroll
  for (int off = 32; off >= 1; off >>= 1) ss += __shfl_xor(ss, off, 64);
  float nr = fmaxf(sqrtf(ss), 1e-12f);
  float en = agg / nr;
  embn[(size_t)n * 64 + lane] = en;
  out[(size_t)n * 64 + lane] += en;
}

extern "C" void kernel_launch(void* const* d_in, const int* in_sizes, int n_in,
                              void* d_out, int out_size, void* d_ws, size_t ws_size,
                              hipStream_t stream) {
  const float* ent    = (const float*)d_in[0];
  const float* weight = (const float*)d_in[1];
  const float* Wq     = (const float*)d_in[2];
  const float* Wk     = (const float*)d_in[3];
  const float* Wv     = (const float*)d_in[4];
  const int*   eidx   = (const int*)d_in[5];
  const int*   etype  = (const int*)d_in[6];
  int N = in_sizes[0] / 64;
  int E = in_sizes[6];
  const int* head = eidx;
  const int* tail = eidx + E;
  int NC = (N + 1) / 2;

  // workspace layout (floats; every block an even float count -> 16B alignment holds)
  float* ws   = (float*)d_ws;
  size_t o = 0;
  float* embA = ws + o; o += (size_t)N * 64;
  float* embB = ws + o; o += (size_t)N * 64;
  float* Gbuf = ws + o; o += (size_t)NC * 256;   // G (chunk), later D (N*32 <= NC*256)
  float* Mf   = ws + o; o += 64 * 256;
  int2* epack = (int2*)(ws + o); o += (size_t)E * 2;
  int* rowptr = (int*)(ws + o); o += N + 1;
  int* deg    = (int*)(ws + o); o += N;
  int* cur    = (int*)(ws + o); o += N;
  int* bsum   = (int*)(ws + o); o += 512;
  int* boff   = (int*)(ws + o); o += 512;
  float* Dbuf = Gbuf;

  int n4  = N * 64 / 4;
  int bl4 = (n4 + BD - 1) / BD;
  int ebl = (E + BD - 1) / BD;
  int nbl = (N + 3) / 4;
  int sbl = (N + BD - 1) / BD;

  k_init<<<bl4, BD, 0, stream>>>((const float4*)ent, (float4*)embA, (float4*)d_out, n4);

  // ---- CSR by head with packed (tail, rt) payload ----
  hipMemsetAsync(deg, 0, (size_t)N * sizeof(int), stream);
  k_deg    <<<ebl, BD, 0, stream>>>(head, deg, E);
  k_scan_a <<<sbl, BD, 0, stream>>>(deg, rowptr, bsum, N);
  k_scan_b <<<1, 512, 0, stream>>>(bsum, boff, sbl);
  k_scan_c <<<sbl, BD, 0, stream>>>(rowptr, boff, N, E);
  k_curinit<<<sbl, BD, 0, stream>>>(rowptr, cur, N);
  k_scatter<<<ebl, BD, 0, stream>>>(head, tail, etype, cur, epack, E);

  float* emb = embA;
  float* alt = embB;
  for (int l = 0; l < 2; l++) {
    const float* wq = Wq + (size_t)l * 64 * 64;
    const float* wk = Wk + (size_t)l * 64 * 64;
    const float* wv = Wv + (size_t)l * 64 * 64;

    k_m<<<64, BD, 0, stream>>>(wq, wk, Mf);
    for (int c = 0; c < 2; c++) {
      int c0 = c * NC, c1 = (c0 + NC < N) ? c0 + NC : N;
      int cn = c1 - c0;
      k_g    <<<(cn + 63) / 64, BD, 0, stream>>>(emb, Mf, (float4*)Gbuf, c0, c1);
      k_fused<<<(cn + 3) / 4, BD, 0, stream>>>(emb, weight, (const float4*)Gbuf, wv,
                                               epack, rowptr, alt, c0, c1);
    }
    k_d<<<(N + 7) / 8, BD, 0, stream>>>(alt, weight, Dbuf, N);
    k_aggnorm<<<nbl, BD, 0, stream>>>(emb, Dbuf, epack, rowptr,
                                      alt, (float*)d_out, N);
    float* tmp = emb; emb = alt; alt = tmp;
  }
}

// Round 4
// 938.696 us; speedup vs baseline: 12.5121x; 1.2866x over previous
//
#include <hip/hip_runtime.h>
#include <math.h>

#define BD 256
#define CAP 192

#define RED16(v) { v += __shfl_xor(v, 1, 64); v += __shfl_xor(v, 2, 64); \
                   v += __shfl_xor(v, 4, 64); v += __shfl_xor(v, 8, 64); }
#define REDQ(v)  { v += __shfl_xor(v, 16, 64); v += __shfl_xor(v, 32, 64); }

// ---------------- init: res = emb_cur = entity_emb ----------------
__global__ void k_init(const float4* __restrict__ ent, float4* __restrict__ emb,
                       float4* __restrict__ out, int n4) {
  int i = blockIdx.x * BD + threadIdx.x;
  if (i < n4) { float4 v = ent[i]; emb[i] = v; out[i] = v; }
}

// ---------------- CSR build ----------------
__global__ void k_deg(const int* __restrict__ head, int* __restrict__ deg, int E) {
  int e = blockIdx.x * BD + threadIdx.x;
  if (e < E) atomicAdd(&deg[head[e]], 1);
}

__global__ void k_scan_a(const int* __restrict__ deg, int* __restrict__ rowptr,
                         int* __restrict__ bsum, int N) {
  __shared__ int s[BD];
  int t = threadIdx.x, i = blockIdx.x * BD + t;
  int v = (i < N) ? deg[i] : 0;
  s[t] = v; __syncthreads();
  for (int off = 1; off < BD; off <<= 1) {
    int add = (t >= off) ? s[t - off] : 0;
    __syncthreads();
    s[t] += add;
    __syncthreads();
  }
  if (i < N) rowptr[i] = s[t] - v;
  if (t == BD - 1) bsum[blockIdx.x] = s[t];
}

__global__ void k_scan_b(const int* __restrict__ bsum, int* __restrict__ boff, int nb) {
  __shared__ int s[512];
  int t = threadIdx.x;
  int v = (t < nb) ? bsum[t] : 0;
  s[t] = v; __syncthreads();
  for (int off = 1; off < 512; off <<= 1) {
    int add = (t >= off) ? s[t - off] : 0;
    __syncthreads();
    s[t] += add;
    __syncthreads();
  }
  boff[t] = s[t] - v;
}

__global__ void k_scan_c(int* __restrict__ rowptr, const int* __restrict__ boff,
                         int N, int E) {
  int i = blockIdx.x * BD + threadIdx.x;
  if (i < N) rowptr[i] += boff[blockIdx.x];
  if (i == 0) rowptr[N] = E;
}

__global__ void k_curinit(const int* __restrict__ rowptr, int* __restrict__ cur, int N) {
  int i = blockIdx.x * BD + threadIdx.x;
  if (i < N) cur[i] = rowptr[i];
}

__global__ void k_scatter(const int* __restrict__ head, const int* __restrict__ tail,
                          const int* __restrict__ etype,
                          int* __restrict__ cur, int2* __restrict__ epack, int E) {
  int e = blockIdx.x * BD + threadIdx.x;
  if (e < E) {
    int p = atomicAdd(&cur[head[e]], 1);
    epack[p] = make_int2(tail[e], etype[e] - 1);
  }
}

// ---------------- M_h = Wq_h @ Wk_h^T : Mf[m][i*4+h] ----------------
__global__ void k_m(const float* __restrict__ Wq, const float* __restrict__ Wk,
                    float* __restrict__ Mf) {
  int tid = blockIdx.x * BD + threadIdx.x;   // 0..16383
  int c = tid & 255;
  int m = tid >> 8;
  int i = c >> 2, h = c & 3;
  const float* wq = Wq + m * 64 + h * 16;
  const float* wk = Wk + i * 64 + h * 16;
  float acc = 0.f;
#pragma unroll
  for (int d = 0; d < 16; d++) acc = fmaf(wq[d], wk[d], acc);
  Mf[tid] = acc;
}

// ---------------- G = emb @ Mf  (LDS-tiled, 64 nodes/block) ----------------
__global__ __launch_bounds__(256) void k_g(const float* __restrict__ emb,
                                           const float* __restrict__ Mf,
                                           float4* __restrict__ G4, int n0, int n1) {
  __shared__ float lM[64 * 256];             // 64 KB
  int t = threadIdx.x;
  const float4* Mf4 = (const float4*)Mf;
  float4* lM4 = (float4*)lM;
  for (int i = t; i < 4096; i += BD) lM4[i] = Mf4[i];
  __syncthreads();
  int lane = t & 63, w = t >> 6;
  int nloc0 = blockIdx.x * 64 + w * 16;
#pragma unroll
  for (int b = 0; b < 2; b++) {
    int nl = nloc0 + b * 8;
    float4 acc[8];
#pragma unroll
    for (int ni = 0; ni < 8; ni++) acc[ni] = make_float4(0.f, 0.f, 0.f, 0.f);
#pragma unroll 8
    for (int m = 0; m < 64; m++) {
      float4 Mv = lM4[m * 64 + lane];
#pragma unroll
      for (int ni = 0; ni < 8; ni++) {
        float em = emb[(size_t)(n0 + nl + ni) * 64 + m];
        acc[ni].x = fmaf(em, Mv.x, acc[ni].x);
        acc[ni].y = fmaf(em, Mv.y, acc[ni].y);
        acc[ni].z = fmaf(em, Mv.z, acc[ni].z);
        acc[ni].w = fmaf(em, Mv.w, acc[ni].w);
      }
    }
#pragma unroll
    for (int ni = 0; ni < 8; ni++)
      if (n0 + nl + ni < n1) G4[(size_t)(nl + ni) * 64 + lane] = acc[ni];
  }
}

// ---------------- fused: att + softmax-den + S + S@Wv -> kg  (quarter-parallel) ----------------
__global__ __launch_bounds__(256) void k_fused(const float* __restrict__ emb,
                        const float* __restrict__ weight,
                        const float4* __restrict__ G4, const float4* __restrict__ Wv4,
                        const int2* __restrict__ epack, const int* __restrict__ rowptr,
                        float* __restrict__ kg, int n0, int n1) {
  __shared__ float WvL[4096];                // 16 KB: Wv[i][j]
  __shared__ float SL[4 * 256];
  int t = threadIdx.x;
  {
    float4* W4 = (float4*)WvL;
    for (int i = t; i < 1024; i += BD) W4[i] = Wv4[i];
  }
  __syncthreads();
  int lane = t & 63, w = t >> 6, q = lane >> 4, s = lane & 15;
  int n = n0 + blockIdx.x * 4 + w;
  if (n >= n1) return;
  const float4* Gn = G4 + (size_t)(n - n0) * 64 + s * 4;
  float4 G0 = Gn[0], G1 = Gn[1], G2 = Gn[2], G3 = Gn[3];
  int base = rowptr[n], deg = rowptr[n + 1] - base;
  float4 den = make_float4(0.f, 0.f, 0.f, 0.f);
  float4 S0 = den, S1 = den, S2 = den, S3 = den;   // S[c] over heads, component s*4+c
  for (int g0 = 0; g0 < deg; g0 += 4) {
    int k = g0 + q;
    bool valid = (k < deg);
    int kk = valid ? k : (deg - 1);
    int2 p = epack[base + kk];
    float4 e4 = *(const float4*)(emb + (size_t)p.x * 64 + s * 4);
    float4 r4 = *(const float4*)(weight + (size_t)p.y * 64 + s * 4);
    float4 x;
    x.x = e4.x * r4.x; x.y = e4.y * r4.y; x.z = e4.z * r4.z; x.w = e4.w * r4.w;
    // att partials over 4 heads
    float4 a;
    a.x = fmaf(x.x, G0.x, fmaf(x.y, G1.x, fmaf(x.z, G2.x, x.w * G3.x)));
    a.y = fmaf(x.x, G0.y, fmaf(x.y, G1.y, fmaf(x.z, G2.y, x.w * G3.y)));
    a.z = fmaf(x.x, G0.z, fmaf(x.y, G1.z, fmaf(x.z, G2.z, x.w * G3.z)));
    a.w = fmaf(x.x, G0.w, fmaf(x.y, G1.w, fmaf(x.z, G2.w, x.w * G3.w)));
    RED16(a.x) RED16(a.y) RED16(a.z) RED16(a.w)
    a.x = fminf(10.f, fmaxf(-10.f, a.x));
    a.y = fminf(10.f, fmaxf(-10.f, a.y));
    a.z = fminf(10.f, fmaxf(-10.f, a.z));
    a.w = fminf(10.f, fmaxf(-10.f, a.w));
    float4 ev;
    ev.x = valid ? __expf(a.x) : 0.f;
    ev.y = valid ? __expf(a.y) : 0.f;
    ev.z = valid ? __expf(a.z) : 0.f;
    ev.w = valid ? __expf(a.w) : 0.f;
    den.x += ev.x; den.y += ev.y; den.z += ev.z; den.w += ev.w;
    S0.x = fmaf(ev.x, x.x, S0.x); S0.y = fmaf(ev.y, x.x, S0.y);
    S0.z = fmaf(ev.z, x.x, S0.z); S0.w = fmaf(ev.w, x.x, S0.w);
    S1.x = fmaf(ev.x, x.y, S1.x); S1.y = fmaf(ev.y, x.y, S1.y);
    S1.z = fmaf(ev.z, x.y, S1.z); S1.w = fmaf(ev.w, x.y, S1.w);
    S2.x = fmaf(ev.x, x.z, S2.x); S2.y = fmaf(ev.y, x.z, S2.y);
    S2.z = fmaf(ev.z, x.z, S2.z); S2.w = fmaf(ev.w, x.z, S2.w);
    S3.x = fmaf(ev.x, x.w, S3.x); S3.y = fmaf(ev.y, x.w, S3.y);
    S3.z = fmaf(ev.z, x.w, S3.z); S3.w = fmaf(ev.w, x.w, S3.w);
  }
  // cross-quarter combine
  REDQ(den.x) REDQ(den.y) REDQ(den.z) REDQ(den.w)
  REDQ(S0.x) REDQ(S0.y) REDQ(S0.z) REDQ(S0.w)
  REDQ(S1.x) REDQ(S1.y) REDQ(S1.z) REDQ(S1.w)
  REDQ(S2.x) REDQ(S2.y) REDQ(S2.z) REDQ(S2.w)
  REDQ(S3.x) REDQ(S3.y) REDQ(S3.z) REDQ(S3.w)
  float4 inv;
  inv.x = 1.f / (den.x + 1e-8f); inv.y = 1.f / (den.y + 1e-8f);
  inv.z = 1.f / (den.z + 1e-8f); inv.w = 1.f / (den.w + 1e-8f);
  S0.x *= inv.x; S0.y *= inv.y; S0.z *= inv.z; S0.w *= inv.w;
  S1.x *= inv.x; S1.y *= inv.y; S1.z *= inv.z; S1.w *= inv.w;
  S2.x *= inv.x; S2.y *= inv.y; S2.z *= inv.z; S2.w *= inv.w;
  S3.x *= inv.x; S3.y *= inv.y; S3.z *= inv.z; S3.w *= inv.w;
  // transpose to LDS (lanes of quarter 0 only; values replicated across quarters)
  float* L = SL + w * 256;
  if (q == 0) {
    L[      s * 4 + 0] = S0.x; L[      s * 4 + 1] = S1.x;
    L[      s * 4 + 2] = S2.x; L[      s * 4 + 3] = S3.x;
    L[ 64 + s * 4 + 0] = S0.y; L[ 64 + s * 4 + 1] = S1.y;
    L[ 64 + s * 4 + 2] = S2.y; L[ 64 + s * 4 + 3] = S3.y;
    L[128 + s * 4 + 0] = S0.z; L[128 + s * 4 + 1] = S1.z;
    L[128 + s * 4 + 2] = S2.z; L[128 + s * 4 + 3] = S3.z;
    L[192 + s * 4 + 0] = S0.w; L[192 + s * 4 + 1] = S1.w;
    L[192 + s * 4 + 2] = S2.w; L[192 + s * 4 + 3] = S3.w;
  }
  // kg[n][lane] = sum_i Snorm[h=q][i] * Wv[i][lane]
  const float4* L4 = (const float4*)(L + q * 64);
  float acc = 0.f;
#pragma unroll
  for (int i4 = 0; i4 < 16; i4++) {
    float4 Lv = L4[i4];
    acc = fmaf(Lv.x, WvL[(i4 * 4 + 0) * 64 + lane], acc);
    acc = fmaf(Lv.y, WvL[(i4 * 4 + 1) * 64 + lane], acc);
    acc = fmaf(Lv.z, WvL[(i4 * 4 + 2) * 64 + lane], acc);
    acc = fmaf(Lv.w, WvL[(i4 * 4 + 3) * 64 + lane], acc);
  }
  kg[(size_t)n * 64 + lane] = acc;
}

// ---------------- D[n][r] = sum_j (kg[n][j]*rel[r][j])^2 ----------------
__global__ void k_d(const float* __restrict__ kg, const float* __restrict__ weight,
                    float* __restrict__ D, int N) {
  int t = threadIdx.x;
  int r = t & 31;
  int n = blockIdx.x * 8 + (t >> 5);
  if (n >= N) return;
  if (r >= 31) { D[(size_t)n * 32 + r] = 0.f; return; }
  const float* kr = kg + (size_t)n * 64;
  const float* wr = weight + (size_t)r * 64;
  float acc = 0.f;
#pragma unroll
  for (int j = 0; j < 64; j++) { float p = kr[j] * wr[j]; acc = fmaf(p, p, acc); }
  D[(size_t)n * 32 + r] = acc;
}

// ---------------- scatter-softmax + aggregation + normalize + residual ----------------
__global__ __launch_bounds__(256) void k_aggnorm(const float* __restrict__ emb,
                          const float* __restrict__ D,
                          const int2* __restrict__ epack, const int* __restrict__ rowptr,
                          float* __restrict__ embn, float* __restrict__ out, int N) {
  __shared__ float wls[4 * CAP];
  __shared__ float DnL[4 * 32];
  int t = threadIdx.x, lane = t & 63, w = t >> 6, q = lane >> 4, s = lane & 15;
  int n = blockIdx.x * 4 + w;
  if (n >= N) return;
  int base = rowptr[n], deg = rowptr[n + 1] - base;
  float* wl = wls + w * CAP;
  float* Dn = DnL + w * 32;
  if (lane < 32) Dn[lane] = (lane < 31) ? D[(size_t)n * 32 + lane] : 0.f;
  float4 agg = make_float4(0.f, 0.f, 0.f, 0.f);
  if (deg > 0) {
    // pass 1: online max/sum over edges (lane-strided)
    float m = -1e30f, ssum = 0.f;
    for (int k = lane; k < deg; k += 64) {
      int2 p = epack[base + k];
      float wv = Dn[p.y] * D[(size_t)p.x * 32 + p.y];
      if (k < CAP) wl[k] = wv;
      float mn = fmaxf(m, wv);
      ssum = ssum * __expf(m - mn) + __expf(wv - mn);
      m = mn;
    }
#pragma unroll
    for (int off = 32; off >= 1; off >>= 1) {
      float mo = __shfl_xor(m, off, 64);
      float so = __shfl_xor(ssum, off, 64);
      float mn = fmaxf(m, mo);
      ssum = ssum * __expf(m - mn) + so * __expf(mo - mn);
      m = mn;
    }
    float inv = 1.f / (ssum + 1e-16f);
    // pass 2: quarter-parallel weighted aggregation
    for (int g0 = 0; g0 < deg; g0 += 4) {
      int k = g0 + q;
      bool valid = (k < deg);
      int kk = valid ? k : (deg - 1);
      int2 p = epack[base + kk];
      float wv = (kk < CAP) ? wl[kk] : Dn[p.y] * D[(size_t)p.x * 32 + p.y];
      float a = valid ? __expf(wv - m) * inv : 0.f;
      float4 e4 = *(const float4*)(emb + (size_t)p.x * 64 + s * 4);
      agg.x = fmaf(a, e4.x, agg.x);
      agg.y = fmaf(a, e4.y, agg.y);
      agg.z = fmaf(a, e4.z, agg.z);
      agg.w = fmaf(a, e4.w, agg.w);
    }
  }
  REDQ(agg.x) REDQ(agg.y) REDQ(agg.z) REDQ(agg.w)
  float ss = agg.x * agg.x + agg.y * agg.y + agg.z * agg.z + agg.w * agg.w;
  RED16(ss)
  float nr = fmaxf(sqrtf(ss), 1e-12f);
  float rin = 1.f / nr;
  float4 en;
  en.x = agg.x * rin; en.y = agg.y * rin; en.z = agg.z * rin; en.w = agg.w * rin;
  if (q == 0) {
    float4* eo = (float4*)(embn + (size_t)n * 64) + s;
    *eo = en;
    float4* oo = (float4*)(out + (size_t)n * 64) + s;
    float4 ov = *oo;
    ov.x += en.x; ov.y += en.y; ov.z += en.z; ov.w += en.w;
    *oo = ov;
  }
}

extern "C" void kernel_launch(void* const* d_in, const int* in_sizes, int n_in,
                              void* d_out, int out_size, void* d_ws, size_t ws_size,
                              hipStream_t stream) {
  const float* ent    = (const float*)d_in[0];
  const float* weight = (const float*)d_in[1];
  const float* Wq     = (const float*)d_in[2];
  const float* Wk     = (const float*)d_in[3];
  const float* Wv     = (const float*)d_in[4];
  const int*   eidx   = (const int*)d_in[5];
  const int*   etype  = (const int*)d_in[6];
  int N = in_sizes[0] / 64;
  int E = in_sizes[6];
  const int* head = eidx;
  const int* tail = eidx + E;
  int NC = (N + 1) / 2;

  float* ws   = (float*)d_ws;
  size_t o = 0;
  float* embA = ws + o; o += (size_t)N * 64;
  float* embB = ws + o; o += (size_t)N * 64;
  float* Gbuf = ws + o; o += (size_t)NC * 256;   // G (chunk), later D (N*32 <= NC*256)
  float* Mf   = ws + o; o += 64 * 256;
  int2* epack = (int2*)(ws + o); o += (size_t)E * 2;
  int* rowptr = (int*)(ws + o); o += N + 1;
  int* deg    = (int*)(ws + o); o += N;
  int* cur    = (int*)(ws + o); o += N;
  int* bsum   = (int*)(ws + o); o += 512;
  int* boff   = (int*)(ws + o); o += 512;
  float* Dbuf = Gbuf;

  int n4  = N * 64 / 4;
  int bl4 = (n4 + BD - 1) / BD;
  int ebl = (E + BD - 1) / BD;
  int nbl = (N + 3) / 4;
  int sbl = (N + BD - 1) / BD;

  k_init<<<bl4, BD, 0, stream>>>((const float4*)ent, (float4*)embA, (float4*)d_out, n4);

  hipMemsetAsync(deg, 0, (size_t)N * sizeof(int), stream);
  k_deg    <<<ebl, BD, 0, stream>>>(head, deg, E);
  k_scan_a <<<sbl, BD, 0, stream>>>(deg, rowptr, bsum, N);
  k_scan_b <<<1, 512, 0, stream>>>(bsum, boff, sbl);
  k_scan_c <<<sbl, BD, 0, stream>>>(rowptr, boff, N, E);
  k_curinit<<<sbl, BD, 0, stream>>>(rowptr, cur, N);
  k_scatter<<<ebl, BD, 0, stream>>>(head, tail, etype, cur, epack, E);

  float* emb = embA;
  float* alt = embB;
  for (int l = 0; l < 2; l++) {
    const float* wq = Wq + (size_t)l * 64 * 64;
    const float* wk = Wk + (size_t)l * 64 * 64;
    const float* wv = Wv + (size_t)l * 64 * 64;

    k_m<<<64, BD, 0, stream>>>(wq, wk, Mf);
    for (int c = 0; c < 2; c++) {
      int c0 = c * NC, c1 = (c0 + NC < N) ? c0 + NC : N;
      int cn = c1 - c0;
      k_g    <<<(cn + 63) / 64, BD, 0, stream>>>(emb, Mf, (float4*)Gbuf, c0, c1);
      k_fused<<<(cn + 3) / 4, BD, 0, stream>>>(emb, weight, (const float4*)Gbuf,
                                               (const float4*)wv, epack, rowptr,
                                               alt, c0, c1);
    }
    k_d<<<(N + 7) / 8, BD, 0, stream>>>(alt, weight, Dbuf, N);
    k_aggnorm<<<nbl, BD, 0, stream>>>(emb, Dbuf, epack, rowptr,
                                      alt, (float*)d_out, N);
    float* tmp = emb; emb = alt; alt = tmp;
  }
}

// Round 5
// 760.662 us; speedup vs baseline: 15.4406x; 1.2341x over previous
//
#include <hip/hip_runtime.h>
#include <math.h>

#define BD 256
#define CAP 192

#define RED16(v) { v += __shfl_xor(v, 1, 64); v += __shfl_xor(v, 2, 64); \
                   v += __shfl_xor(v, 4, 64); v += __shfl_xor(v, 8, 64); }
#define REDQ(v)  { v += __shfl_xor(v, 16, 64); v += __shfl_xor(v, 32, 64); }

// ---------------- init: res = emb_cur = entity_emb ----------------
__global__ void k_init(const float4* __restrict__ ent, float4* __restrict__ emb,
                       float4* __restrict__ out, int n4) {
  int i = blockIdx.x * BD + threadIdx.x;
  if (i < n4) { float4 v = ent[i]; emb[i] = v; out[i] = v; }
}

// ---------------- CSR build ----------------
__global__ void k_deg(const int* __restrict__ head, int* __restrict__ deg, int E) {
  int e = blockIdx.x * BD + threadIdx.x;
  if (e < E) atomicAdd(&deg[head[e]], 1);
}

__global__ void k_scan_a(const int* __restrict__ deg, int* __restrict__ rowptr,
                         int* __restrict__ bsum, int N) {
  __shared__ int s[BD];
  int t = threadIdx.x, i = blockIdx.x * BD + t;
  int v = (i < N) ? deg[i] : 0;
  s[t] = v; __syncthreads();
  for (int off = 1; off < BD; off <<= 1) {
    int add = (t >= off) ? s[t - off] : 0;
    __syncthreads();
    s[t] += add;
    __syncthreads();
  }
  if (i < N) rowptr[i] = s[t] - v;
  if (t == BD - 1) bsum[blockIdx.x] = s[t];
}

__global__ void k_scan_b(const int* __restrict__ bsum, int* __restrict__ boff, int nb) {
  __shared__ int s[512];
  int t = threadIdx.x;
  int v = (t < nb) ? bsum[t] : 0;
  s[t] = v; __syncthreads();
  for (int off = 1; off < 512; off <<= 1) {
    int add = (t >= off) ? s[t - off] : 0;
    __syncthreads();
    s[t] += add;
    __syncthreads();
  }
  boff[t] = s[t] - v;
}

__global__ void k_scan_c(int* __restrict__ rowptr, const int* __restrict__ boff,
                         int N, int E) {
  int i = blockIdx.x * BD + threadIdx.x;
  if (i < N) rowptr[i] += boff[blockIdx.x];
  if (i == 0) rowptr[N] = E;
}

__global__ void k_curinit(const int* __restrict__ rowptr, int* __restrict__ cur, int N) {
  int i = blockIdx.x * BD + threadIdx.x;
  if (i < N) cur[i] = rowptr[i];
}

__global__ void k_scatter(const int* __restrict__ head, const int* __restrict__ tail,
                          const int* __restrict__ etype,
                          int* __restrict__ cur, int2* __restrict__ epack, int E) {
  int e = blockIdx.x * BD + threadIdx.x;
  if (e < E) {
    int p = atomicAdd(&cur[head[e]], 1);
    epack[p] = make_int2(tail[e], etype[e] - 1);
  }
}

// ---------------- M_h = Wq_h @ Wk_h^T : Mf[m][i*4+h] ----------------
__global__ void k_m(const float* __restrict__ Wq, const float* __restrict__ Wk,
                    float* __restrict__ Mf) {
  int tid = blockIdx.x * BD + threadIdx.x;   // 0..16383
  int c = tid & 255;
  int m = tid >> 8;
  int i = c >> 2, h = c & 3;
  const float* wq = Wq + m * 64 + h * 16;
  const float* wk = Wk + i * 64 + h * 16;
  float acc = 0.f;
#pragma unroll
  for (int d = 0; d < 16; d++) acc = fmaf(wq[d], wk[d], acc);
  Mf[tid] = acc;
}

// ---------------- G = emb @ Mf  (LDS-tiled, 64 nodes/block) ----------------
__global__ __launch_bounds__(256) void k_g(const float* __restrict__ emb,
                                           const float* __restrict__ Mf,
                                           float4* __restrict__ G4, int n0, int n1) {
  __shared__ float lM[64 * 256];             // 64 KB
  int t = threadIdx.x;
  const float4* Mf4 = (const float4*)Mf;
  float4* lM4 = (float4*)lM;
  for (int i = t; i < 4096; i += BD) lM4[i] = Mf4[i];
  __syncthreads();
  int lane = t & 63, w = t >> 6;
  int nloc0 = blockIdx.x * 64 + w * 16;
#pragma unroll
  for (int b = 0; b < 2; b++) {
    int nl = nloc0 + b * 8;
    float4 acc[8];
#pragma unroll
    for (int ni = 0; ni < 8; ni++) acc[ni] = make_float4(0.f, 0.f, 0.f, 0.f);
#pragma unroll 8
    for (int m = 0; m < 64; m++) {
      float4 Mv = lM4[m * 64 + lane];
#pragma unroll
      for (int ni = 0; ni < 8; ni++) {
        float em = emb[(size_t)(n0 + nl + ni) * 64 + m];
        acc[ni].x = fmaf(em, Mv.x, acc[ni].x);
        acc[ni].y = fmaf(em, Mv.y, acc[ni].y);
        acc[ni].z = fmaf(em, Mv.z, acc[ni].z);
        acc[ni].w = fmaf(em, Mv.w, acc[ni].w);
      }
    }
#pragma unroll
    for (int ni = 0; ni < 8; ni++)
      if (n0 + nl + ni < n1) G4[(size_t)(nl + ni) * 64 + lane] = acc[ni];
  }
}

// ---------------- fused: att + softmax-den + S + S@Wv -> kg  (quarter-parallel) ----------------
__global__ __launch_bounds__(256) void k_fused(const float* __restrict__ emb,
                        const float* __restrict__ weight,
                        const float4* __restrict__ G4, const float4* __restrict__ Wv4,
                        const int2* __restrict__ epack, const int* __restrict__ rowptr,
                        float* __restrict__ kg, int n0, int n1) {
  __shared__ float WvL[4096];                // 16 KB: Wv[i][j]
  __shared__ float SL[4 * 256];
  int t = threadIdx.x;
  {
    float4* W4 = (float4*)WvL;
    for (int i = t; i < 1024; i += BD) W4[i] = Wv4[i];
  }
  __syncthreads();
  int lane = t & 63, w = t >> 6, q = lane >> 4, s = lane & 15;
  int n = n0 + blockIdx.x * 4 + w;
  if (n >= n1) return;
  const float4* Gn = G4 + (size_t)(n - n0) * 64 + s * 4;
  float4 G0 = Gn[0], G1 = Gn[1], G2 = Gn[2], G3 = Gn[3];
  int base = rowptr[n], deg = rowptr[n + 1] - base;
  float4 den = make_float4(0.f, 0.f, 0.f, 0.f);
  float4 S0 = den, S1 = den, S2 = den, S3 = den;   // S[c] over heads, component s*4+c
#pragma unroll 2
  for (int g0 = 0; g0 < deg; g0 += 4) {
    int k = g0 + q;
    bool valid = (k < deg);
    int kk = valid ? k : (deg - 1);
    int2 p = epack[base + kk];
    float4 e4 = *(const float4*)(emb + (size_t)p.x * 64 + s * 4);
    float4 r4 = *(const float4*)(weight + (size_t)p.y * 64 + s * 4);
    float4 x;
    x.x = e4.x * r4.x; x.y = e4.y * r4.y; x.z = e4.z * r4.z; x.w = e4.w * r4.w;
    // att partials over 4 heads
    float4 a;
    a.x = fmaf(x.x, G0.x, fmaf(x.y, G1.x, fmaf(x.z, G2.x, x.w * G3.x)));
    a.y = fmaf(x.x, G0.y, fmaf(x.y, G1.y, fmaf(x.z, G2.y, x.w * G3.y)));
    a.z = fmaf(x.x, G0.z, fmaf(x.y, G1.z, fmaf(x.z, G2.z, x.w * G3.z)));
    a.w = fmaf(x.x, G0.w, fmaf(x.y, G1.w, fmaf(x.z, G2.w, x.w * G3.w)));
    RED16(a.x) RED16(a.y) RED16(a.z) RED16(a.w)
    a.x = fminf(10.f, fmaxf(-10.f, a.x));
    a.y = fminf(10.f, fmaxf(-10.f, a.y));
    a.z = fminf(10.f, fmaxf(-10.f, a.z));
    a.w = fminf(10.f, fmaxf(-10.f, a.w));
    float4 ev;
    ev.x = valid ? __expf(a.x) : 0.f;
    ev.y = valid ? __expf(a.y) : 0.f;
    ev.z = valid ? __expf(a.z) : 0.f;
    ev.w = valid ? __expf(a.w) : 0.f;
    den.x += ev.x; den.y += ev.y; den.z += ev.z; den.w += ev.w;
    S0.x = fmaf(ev.x, x.x, S0.x); S0.y = fmaf(ev.y, x.x, S0.y);
    S0.z = fmaf(ev.z, x.x, S0.z); S0.w = fmaf(ev.w, x.x, S0.w);
    S1.x = fmaf(ev.x, x.y, S1.x); S1.y = fmaf(ev.y, x.y, S1.y);
    S1.z = fmaf(ev.z, x.y, S1.z); S1.w = fmaf(ev.w, x.y, S1.w);
    S2.x = fmaf(ev.x, x.z, S2.x); S2.y = fmaf(ev.y, x.z, S2.y);
    S2.z = fmaf(ev.z, x.z, S2.z); S2.w = fmaf(ev.w, x.z, S2.w);
    S3.x = fmaf(ev.x, x.w, S3.x); S3.y = fmaf(ev.y, x.w, S3.y);
    S3.z = fmaf(ev.z, x.w, S3.z); S3.w = fmaf(ev.w, x.w, S3.w);
  }
  // cross-quarter combine
  REDQ(den.x) REDQ(den.y) REDQ(den.z) REDQ(den.w)
  REDQ(S0.x) REDQ(S0.y) REDQ(S0.z) REDQ(S0.w)
  REDQ(S1.x) REDQ(S1.y) REDQ(S1.z) REDQ(S1.w)
  REDQ(S2.x) REDQ(S2.y) REDQ(S2.z) REDQ(S2.w)
  REDQ(S3.x) REDQ(S3.y) REDQ(S3.z) REDQ(S3.w)
  float4 inv;
  inv.x = 1.f / (den.x + 1e-8f); inv.y = 1.f / (den.y + 1e-8f);
  inv.z = 1.f / (den.z + 1e-8f); inv.w = 1.f / (den.w + 1e-8f);
  S0.x *= inv.x; S0.y *= inv.y; S0.z *= inv.z; S0.w *= inv.w;
  S1.x *= inv.x; S1.y *= inv.y; S1.z *= inv.z; S1.w *= inv.w;
  S2.x *= inv.x; S2.y *= inv.y; S2.z *= inv.z; S2.w *= inv.w;
  S3.x *= inv.x; S3.y *= inv.y; S3.z *= inv.z; S3.w *= inv.w;
  // transpose to LDS (lanes of quarter 0 only; values replicated across quarters)
  float* L = SL + w * 256;
  if (q == 0) {
    L[      s * 4 + 0] = S0.x; L[      s * 4 + 1] = S1.x;
    L[      s * 4 + 2] = S2.x; L[      s * 4 + 3] = S3.x;
    L[ 64 + s * 4 + 0] = S0.y; L[ 64 + s * 4 + 1] = S1.y;
    L[ 64 + s * 4 + 2] = S2.y; L[ 64 + s * 4 + 3] = S3.y;
    L[128 + s * 4 + 0] = S0.z; L[128 + s * 4 + 1] = S1.z;
    L[128 + s * 4 + 2] = S2.z; L[128 + s * 4 + 3] = S3.z;
    L[192 + s * 4 + 0] = S0.w; L[192 + s * 4 + 1] = S1.w;
    L[192 + s * 4 + 2] = S2.w; L[192 + s * 4 + 3] = S3.w;
  }
  // kg[n][lane] = sum_i Snorm[h=q][i] * Wv[i][lane]
  const float4* L4 = (const float4*)(L + q * 64);
  float acc = 0.f;
#pragma unroll
  for (int i4 = 0; i4 < 16; i4++) {
    float4 Lv = L4[i4];
    acc = fmaf(Lv.x, WvL[(i4 * 4 + 0) * 64 + lane], acc);
    acc = fmaf(Lv.y, WvL[(i4 * 4 + 1) * 64 + lane], acc);
    acc = fmaf(Lv.z, WvL[(i4 * 4 + 2) * 64 + lane], acc);
    acc = fmaf(Lv.w, WvL[(i4 * 4 + 3) * 64 + lane], acc);
  }
  kg[(size_t)n * 64 + lane] = acc;
}

// ---------------- D = KG^2 @ REL^2T  (64 nodes/block, LDS-staged) ----------------
__global__ __launch_bounds__(256) void k_d(const float4* __restrict__ kg4,
                    const float* __restrict__ weight,
                    float* __restrict__ D, int N) {
  __shared__ float R2T[64 * 32];       // [j][r] = weight[r][j]^2, conflict-free col reads
  __shared__ float KG2[64 * 68];       // [node][j] padded
  int t = threadIdx.x;
  // stage weight^2 transposed: i = j*32+r (consecutive writes conflict-free)
  for (int i = t; i < 2048; i += BD) {
    int j = i >> 5, r = i & 31;
    float v = (r < 31) ? weight[r * 64 + j] : 0.f;
    R2T[i] = v * v;
  }
  // stage kg^2 for 64 nodes (coalesced float4 reads)
  int nbase = blockIdx.x * 64;
  const float4* src = kg4 + (size_t)nbase * 16;
#pragma unroll
  for (int i = 0; i < 4; i++) {
    int idx = t + i * 256;             // 0..1023
    float4 v = src[idx];               // may over-read past N into adjacent ws: safe
    float* dst = KG2 + (idx >> 4) * 68 + (idx & 15) * 4;
    dst[0] = v.x * v.x; dst[1] = v.y * v.y; dst[2] = v.z * v.z; dst[3] = v.w * v.w;
  }
  __syncthreads();
  int r = t & 31, ng = t >> 5;         // thread: relation r, nodes ng*8..ng*8+7
  float acc[8] = {0.f, 0.f, 0.f, 0.f, 0.f, 0.f, 0.f, 0.f};
  const float* kbase = KG2 + ng * 8 * 68;
#pragma unroll 4
  for (int j4 = 0; j4 < 16; j4++) {
    float r0 = R2T[(j4 * 4 + 0) * 32 + r];
    float r1 = R2T[(j4 * 4 + 1) * 32 + r];
    float r2 = R2T[(j4 * 4 + 2) * 32 + r];
    float r3 = R2T[(j4 * 4 + 3) * 32 + r];
#pragma unroll
    for (int ni = 0; ni < 8; ni++) {
      float4 kv = *(const float4*)(kbase + ni * 68 + j4 * 4);   // broadcast read
      acc[ni] = fmaf(kv.w, r3, fmaf(kv.z, r2, fmaf(kv.y, r1, fmaf(kv.x, r0, acc[ni]))));
    }
  }
  if (r < 31) {
    int nlim = N - nbase;
#pragma unroll
    for (int ni = 0; ni < 8; ni++) {
      int nl = ng * 8 + ni;
      if (nl < nlim) D[(size_t)(nbase + nl) * 32 + r] = acc[ni];
    }
  }
}

// ---------------- scatter-softmax + aggregation + normalize + residual ----------------
__global__ __launch_bounds__(256) void k_aggnorm(const float* __restrict__ emb,
                          const float* __restrict__ D,
                          const int2* __restrict__ epack, const int* __restrict__ rowptr,
                          float* __restrict__ embn, float* __restrict__ out, int N) {
  __shared__ float wls[4 * CAP];
  __shared__ float DnL[4 * 32];
  int t = threadIdx.x, lane = t & 63, w = t >> 6, q = lane >> 4, s = lane & 15;
  int n = blockIdx.x * 4 + w;
  if (n >= N) return;
  int base = rowptr[n], deg = rowptr[n + 1] - base;
  float* wl = wls + w * CAP;
  float* Dn = DnL + w * 32;
  if (lane < 32) Dn[lane] = (lane < 31) ? D[(size_t)n * 32 + lane] : 0.f;
  float4 agg = make_float4(0.f, 0.f, 0.f, 0.f);
  if (deg > 0) {
    // pass 1: online max/sum over edges (lane-strided)
    float m = -1e30f, ssum = 0.f;
    for (int k = lane; k < deg; k += 64) {
      int2 p = epack[base + k];
      float wv = Dn[p.y] * D[(size_t)p.x * 32 + p.y];
      if (k < CAP) wl[k] = wv;
      float mn = fmaxf(m, wv);
      ssum = ssum * __expf(m - mn) + __expf(wv - mn);
      m = mn;
    }
#pragma unroll
    for (int off = 32; off >= 1; off >>= 1) {
      float mo = __shfl_xor(m, off, 64);
      float so = __shfl_xor(ssum, off, 64);
      float mn = fmaxf(m, mo);
      ssum = ssum * __expf(m - mn) + so * __expf(mo - mn);
      m = mn;
    }
    float inv = 1.f / (ssum + 1e-16f);
    // pass 2: quarter-parallel weighted aggregation
#pragma unroll 2
    for (int g0 = 0; g0 < deg; g0 += 4) {
      int k = g0 + q;
      bool valid = (k < deg);
      int kk = valid ? k : (deg - 1);
      int2 p = epack[base + kk];
      float wv = (kk < CAP) ? wl[kk] : Dn[p.y] * D[(size_t)p.x * 32 + p.y];
      float a = valid ? __expf(wv - m) * inv : 0.f;
      float4 e4 = *(const float4*)(emb + (size_t)p.x * 64 + s * 4);
      agg.x = fmaf(a, e4.x, agg.x);
      agg.y = fmaf(a, e4.y, agg.y);
      agg.z = fmaf(a, e4.z, agg.z);
      agg.w = fmaf(a, e4.w, agg.w);
    }
  }
  REDQ(agg.x) REDQ(agg.y) REDQ(agg.z) REDQ(agg.w)
  float ss = agg.x * agg.x + agg.y * agg.y + agg.z * agg.z + agg.w * agg.w;
  RED16(ss)
  float nr = fmaxf(sqrtf(ss), 1e-12f);
  float rin = 1.f / nr;
  float4 en;
  en.x = agg.x * rin; en.y = agg.y * rin; en.z = agg.z * rin; en.w = agg.w * rin;
  if (q == 0) {
    float4* eo = (float4*)(embn + (size_t)n * 64) + s;
    *eo = en;
    float4* oo = (float4*)(out + (size_t)n * 64) + s;
    float4 ov = *oo;
    ov.x += en.x; ov.y += en.y; ov.z += en.z; ov.w += en.w;
    *oo = ov;
  }
}

extern "C" void kernel_launch(void* const* d_in, const int* in_sizes, int n_in,
                              void* d_out, int out_size, void* d_ws, size_t ws_size,
                              hipStream_t stream) {
  const float* ent    = (const float*)d_in[0];
  const float* weight = (const float*)d_in[1];
  const float* Wq     = (const float*)d_in[2];
  const float* Wk     = (const float*)d_in[3];
  const float* Wv     = (const float*)d_in[4];
  const int*   eidx   = (const int*)d_in[5];
  const int*   etype  = (const int*)d_in[6];
  int N = in_sizes[0] / 64;
  int E = in_sizes[6];
  const int* head = eidx;
  const int* tail = eidx + E;
  int NC = (N + 1) / 2;

  float* ws   = (float*)d_ws;
  size_t o = 0;
  float* embA = ws + o; o += (size_t)N * 64;
  float* embB = ws + o; o += (size_t)N * 64;
  float* Gbuf = ws + o; o += (size_t)NC * 256;   // G (chunk), later D (N*32 <= NC*256)
  float* Mf   = ws + o; o += 64 * 256;
  int2* epack = (int2*)(ws + o); o += (size_t)E * 2;
  int* rowptr = (int*)(ws + o); o += N + 1;
  int* deg    = (int*)(ws + o); o += N;
  int* cur    = (int*)(ws + o); o += N;
  int* bsum   = (int*)(ws + o); o += 512;
  int* boff   = (int*)(ws + o); o += 512;
  float* Dbuf = Gbuf;

  int n4  = N * 64 / 4;
  int bl4 = (n4 + BD - 1) / BD;
  int ebl = (E + BD - 1) / BD;
  int nbl = (N + 3) / 4;
  int sbl = (N + BD - 1) / BD;

  k_init<<<bl4, BD, 0, stream>>>((const float4*)ent, (float4*)embA, (float4*)d_out, n4);

  hipMemsetAsync(deg, 0, (size_t)N * sizeof(int), stream);
  k_deg    <<<ebl, BD, 0, stream>>>(head, deg, E);
  k_scan_a <<<sbl, BD, 0, stream>>>(deg, rowptr, bsum, N);
  k_scan_b <<<1, 512, 0, stream>>>(bsum, boff, sbl);
  k_scan_c <<<sbl, BD, 0, stream>>>(rowptr, boff, N, E);
  k_curinit<<<sbl, BD, 0, stream>>>(rowptr, cur, N);
  k_scatter<<<ebl, BD, 0, stream>>>(head, tail, etype, cur, epack, E);

  float* emb = embA;
  float* alt = embB;
  for (int l = 0; l < 2; l++) {
    const float* wq = Wq + (size_t)l * 64 * 64;
    const float* wk = Wk + (size_t)l * 64 * 64;
    const float* wv = Wv + (size_t)l * 64 * 64;

    k_m<<<64, BD, 0, stream>>>(wq, wk, Mf);
    for (int c = 0; c < 2; c++) {
      int c0 = c * NC, c1 = (c0 + NC < N) ? c0 + NC : N;
      int cn = c1 - c0;
      k_g    <<<(cn + 63) / 64, BD, 0, stream>>>(emb, Mf, (float4*)Gbuf, c0, c1);
      k_fused<<<(cn + 3) / 4, BD, 0, stream>>>(emb, weight, (const float4*)Gbuf,
                                               (const float4*)wv, epack, rowptr,
                                               alt, c0, c1);
    }
    k_d<<<(N + 63) / 64, BD, 0, stream>>>((const float4*)alt, weight, Dbuf, N);
    k_aggnorm<<<nbl, BD, 0, stream>>>(emb, Dbuf, epack, rowptr,
                                      alt, (float*)d_out, N);
    float* tmp = emb; emb = alt; alt = tmp;
  }
}

// Round 6
// 731.514 us; speedup vs baseline: 16.0559x; 1.0398x over previous
//
#include <hip/hip_runtime.h>
#include <math.h>

#define BD 256
#define CAP 192

#define RED16(v) { v += __shfl_xor(v, 1, 64); v += __shfl_xor(v, 2, 64); \
                   v += __shfl_xor(v, 4, 64); v += __shfl_xor(v, 8, 64); }
#define REDQ(v)  { v += __shfl_xor(v, 16, 64); v += __shfl_xor(v, 32, 64); }

// ---------------- init: res = emb_cur = entity_emb ----------------
__global__ void k_init(const float4* __restrict__ ent, float4* __restrict__ emb,
                       float4* __restrict__ out, int n4) {
  int i = blockIdx.x * BD + threadIdx.x;
  if (i < n4) { float4 v = ent[i]; emb[i] = v; out[i] = v; }
}

// ---------------- CSR build ----------------
__global__ void k_deg(const int* __restrict__ head, int* __restrict__ deg, int E) {
  int e = blockIdx.x * BD + threadIdx.x;
  if (e < E) atomicAdd(&deg[head[e]], 1);
}

__global__ void k_scan_a(const int* __restrict__ deg, int* __restrict__ rowptr,
                         int* __restrict__ bsum, int N) {
  __shared__ int s[BD];
  int t = threadIdx.x, i = blockIdx.x * BD + t;
  int v = (i < N) ? deg[i] : 0;
  s[t] = v; __syncthreads();
  for (int off = 1; off < BD; off <<= 1) {
    int add = (t >= off) ? s[t - off] : 0;
    __syncthreads();
    s[t] += add;
    __syncthreads();
  }
  if (i < N) rowptr[i] = s[t] - v;
  if (t == BD - 1) bsum[blockIdx.x] = s[t];
}

__global__ void k_scan_b(const int* __restrict__ bsum, int* __restrict__ boff, int nb) {
  __shared__ int s[512];
  int t = threadIdx.x;
  int v = (t < nb) ? bsum[t] : 0;
  s[t] = v; __syncthreads();
  for (int off = 1; off < 512; off <<= 1) {
    int add = (t >= off) ? s[t - off] : 0;
    __syncthreads();
    s[t] += add;
    __syncthreads();
  }
  boff[t] = s[t] - v;
}

__global__ void k_scan_c(int* __restrict__ rowptr, const int* __restrict__ boff,
                         int N, int E) {
  int i = blockIdx.x * BD + threadIdx.x;
  if (i < N) rowptr[i] += boff[blockIdx.x];
  if (i == 0) rowptr[N] = E;
}

__global__ void k_curinit(const int* __restrict__ rowptr, int* __restrict__ cur, int N) {
  int i = blockIdx.x * BD + threadIdx.x;
  if (i < N) cur[i] = rowptr[i];
}

__global__ void k_scatter(const int* __restrict__ head, const int* __restrict__ tail,
                          const int* __restrict__ etype,
                          int* __restrict__ cur, int2* __restrict__ epack, int E) {
  int e = blockIdx.x * BD + threadIdx.x;
  if (e < E) {
    int p = atomicAdd(&cur[head[e]], 1);
    epack[p] = make_int2(tail[e], etype[e] - 1);
  }
}

// ---------------- M_h = Wq_h @ Wk_h^T : Mf[m][i*4+h] ----------------
__global__ void k_m(const float* __restrict__ Wq, const float* __restrict__ Wk,
                    float* __restrict__ Mf) {
  int tid = blockIdx.x * BD + threadIdx.x;   // 0..16383
  int c = tid & 255;
  int m = tid >> 8;
  int i = c >> 2, h = c & 3;
  const float* wq = Wq + m * 64 + h * 16;
  const float* wk = Wk + i * 64 + h * 16;
  float acc = 0.f;
#pragma unroll
  for (int d = 0; d < 16; d++) acc = fmaf(wq[d], wk[d], acc);
  Mf[tid] = acc;
}

// ---------------- G = emb @ Mf  (LDS-tiled, 64 nodes/block) ----------------
__global__ __launch_bounds__(256) void k_g(const float* __restrict__ emb,
                                           const float* __restrict__ Mf,
                                           float4* __restrict__ G4, int n0, int n1) {
  __shared__ float lM[64 * 256];             // 64 KB
  int t = threadIdx.x;
  const float4* Mf4 = (const float4*)Mf;
  float4* lM4 = (float4*)lM;
  for (int i = t; i < 4096; i += BD) lM4[i] = Mf4[i];
  __syncthreads();
  int lane = t & 63, w = t >> 6;
  int nloc0 = blockIdx.x * 64 + w * 16;
#pragma unroll
  for (int b = 0; b < 2; b++) {
    int nl = nloc0 + b * 8;
    float4 acc[8];
#pragma unroll
    for (int ni = 0; ni < 8; ni++) acc[ni] = make_float4(0.f, 0.f, 0.f, 0.f);
#pragma unroll 8
    for (int m = 0; m < 64; m++) {
      float4 Mv = lM4[m * 64 + lane];
#pragma unroll
      for (int ni = 0; ni < 8; ni++) {
        float em = emb[(size_t)(n0 + nl + ni) * 64 + m];
        acc[ni].x = fmaf(em, Mv.x, acc[ni].x);
        acc[ni].y = fmaf(em, Mv.y, acc[ni].y);
        acc[ni].z = fmaf(em, Mv.z, acc[ni].z);
        acc[ni].w = fmaf(em, Mv.w, acc[ni].w);
      }
    }
#pragma unroll
    for (int ni = 0; ni < 8; ni++)
      if (n0 + nl + ni < n1) G4[(size_t)(nl + ni) * 64 + lane] = acc[ni];
  }
}

// ---------------- fused: att + softmax-den + S + S@Wv -> kg  (quarter-parallel, prefetched) ----------------
__global__ __launch_bounds__(256) void k_fused(const float* __restrict__ emb,
                        const float* __restrict__ weight,
                        const float4* __restrict__ G4, const float* __restrict__ Wv,
                        const int2* __restrict__ epack, const int* __restrict__ rowptr,
                        float* __restrict__ kg, int n0, int n1) {
  __shared__ float SL[4 * 272];              // per-wave 4 segments of 68 (bank-skewed)
  int t = threadIdx.x, lane = t & 63, w = t >> 6, q = lane >> 4, s = lane & 15;
  int n = n0 + blockIdx.x * 4 + w;
  if (n >= n1) return;
  const float4* Gn = G4 + (size_t)(n - n0) * 64 + s * 4;
  float4 G0 = Gn[0], G1 = Gn[1], G2 = Gn[2], G3 = Gn[3];
  int base = rowptr[n], deg = rowptr[n + 1] - base;
  float4 den = make_float4(0.f, 0.f, 0.f, 0.f);
  float4 S0 = den, S1 = den, S2 = den, S3 = den;   // S[c] over heads, component s*4+c
  if (deg > 0) {
    bool valid = (q < deg);
    int kk = valid ? q : (deg - 1);
    int2 p = epack[base + kk];
    float4 e4 = *(const float4*)(emb + (size_t)p.x * 64 + s * 4);
    float4 r4 = *(const float4*)(weight + (size_t)p.y * 64 + s * 4);
    for (int g0 = 0; g0 < deg; g0 += 4) {
      // prefetch next group (wave-uniform branch)
      int2 pn = p; float4 e4n = e4, r4n = r4; bool validn = false;
      if (g0 + 4 < deg) {
        int kn = g0 + 4 + q;
        validn = (kn < deg);
        int kkn = validn ? kn : (deg - 1);
        pn = epack[base + kkn];
        e4n = *(const float4*)(emb + (size_t)pn.x * 64 + s * 4);
        r4n = *(const float4*)(weight + (size_t)pn.y * 64 + s * 4);
      }
      // compute current group
      float4 x;
      x.x = e4.x * r4.x; x.y = e4.y * r4.y; x.z = e4.z * r4.z; x.w = e4.w * r4.w;
      float4 a;
      a.x = fmaf(x.x, G0.x, fmaf(x.y, G1.x, fmaf(x.z, G2.x, x.w * G3.x)));
      a.y = fmaf(x.x, G0.y, fmaf(x.y, G1.y, fmaf(x.z, G2.y, x.w * G3.y)));
      a.z = fmaf(x.x, G0.z, fmaf(x.y, G1.z, fmaf(x.z, G2.z, x.w * G3.z)));
      a.w = fmaf(x.x, G0.w, fmaf(x.y, G1.w, fmaf(x.z, G2.w, x.w * G3.w)));
      RED16(a.x) RED16(a.y) RED16(a.z) RED16(a.w)
      a.x = fminf(10.f, fmaxf(-10.f, a.x));
      a.y = fminf(10.f, fmaxf(-10.f, a.y));
      a.z = fminf(10.f, fmaxf(-10.f, a.z));
      a.w = fminf(10.f, fmaxf(-10.f, a.w));
      float4 ev;
      ev.x = valid ? __expf(a.x) : 0.f;
      ev.y = valid ? __expf(a.y) : 0.f;
      ev.z = valid ? __expf(a.z) : 0.f;
      ev.w = valid ? __expf(a.w) : 0.f;
      den.x += ev.x; den.y += ev.y; den.z += ev.z; den.w += ev.w;
      S0.x = fmaf(ev.x, x.x, S0.x); S0.y = fmaf(ev.y, x.x, S0.y);
      S0.z = fmaf(ev.z, x.x, S0.z); S0.w = fmaf(ev.w, x.x, S0.w);
      S1.x = fmaf(ev.x, x.y, S1.x); S1.y = fmaf(ev.y, x.y, S1.y);
      S1.z = fmaf(ev.z, x.y, S1.z); S1.w = fmaf(ev.w, x.y, S1.w);
      S2.x = fmaf(ev.x, x.z, S2.x); S2.y = fmaf(ev.y, x.z, S2.y);
      S2.z = fmaf(ev.z, x.z, S2.z); S2.w = fmaf(ev.w, x.z, S2.w);
      S3.x = fmaf(ev.x, x.w, S3.x); S3.y = fmaf(ev.y, x.w, S3.y);
      S3.z = fmaf(ev.z, x.w, S3.z); S3.w = fmaf(ev.w, x.w, S3.w);
      p = pn; e4 = e4n; r4 = r4n; valid = validn;
    }
  }
  // cross-quarter combine
  REDQ(den.x) REDQ(den.y) REDQ(den.z) REDQ(den.w)
  REDQ(S0.x) REDQ(S0.y) REDQ(S0.z) REDQ(S0.w)
  REDQ(S1.x) REDQ(S1.y) REDQ(S1.z) REDQ(S1.w)
  REDQ(S2.x) REDQ(S2.y) REDQ(S2.z) REDQ(S2.w)
  REDQ(S3.x) REDQ(S3.y) REDQ(S3.z) REDQ(S3.w)
  float4 inv;
  inv.x = 1.f / (den.x + 1e-8f); inv.y = 1.f / (den.y + 1e-8f);
  inv.z = 1.f / (den.z + 1e-8f); inv.w = 1.f / (den.w + 1e-8f);
  S0.x *= inv.x; S0.y *= inv.y; S0.z *= inv.z; S0.w *= inv.w;
  S1.x *= inv.x; S1.y *= inv.y; S1.z *= inv.z; S1.w *= inv.w;
  S2.x *= inv.x; S2.y *= inv.y; S2.z *= inv.z; S2.w *= inv.w;
  S3.x *= inv.x; S3.y *= inv.y; S3.z *= inv.z; S3.w *= inv.w;
  // transpose to LDS: segment h at offset h*68 (bank-skewed), float4 writes by quarter 0
  float* L = SL + w * 272;
  if (q == 0) {
    *(float4*)(L +       s * 4) = make_float4(S0.x, S1.x, S2.x, S3.x);
    *(float4*)(L +  68 + s * 4) = make_float4(S0.y, S1.y, S2.y, S3.y);
    *(float4*)(L + 136 + s * 4) = make_float4(S0.z, S1.z, S2.z, S3.z);
    *(float4*)(L + 204 + s * 4) = make_float4(S0.w, S1.w, S2.w, S3.w);
  }
  // kg[n][lane] = sum_i Snorm[h=q][i] * Wv[i][lane]  (Wv direct: 16 KB, L1-resident)
  const float4* L4 = (const float4*)(L + q * 68);
  float acc = 0.f;
#pragma unroll
  for (int i4 = 0; i4 < 16; i4++) {
    float4 Lv = L4[i4];
    acc = fmaf(Lv.x, Wv[(i4 * 4 + 0) * 64 + lane], acc);
    acc = fmaf(Lv.y, Wv[(i4 * 4 + 1) * 64 + lane], acc);
    acc = fmaf(Lv.z, Wv[(i4 * 4 + 2) * 64 + lane], acc);
    acc = fmaf(Lv.w, Wv[(i4 * 4 + 3) * 64 + lane], acc);
  }
  kg[(size_t)n * 64 + lane] = acc;
}

// ---------------- D = KG^2 @ REL^2T  (64 nodes/block, LDS-staged) ----------------
__global__ __launch_bounds__(256) void k_d(const float4* __restrict__ kg4,
                    const float* __restrict__ weight,
                    float* __restrict__ D, int N) {
  __shared__ float R2T[64 * 32];       // [j][r] = weight[r][j]^2
  __shared__ float KG2[64 * 68];       // [node][j] padded
  int t = threadIdx.x;
  for (int i = t; i < 2048; i += BD) {
    int j = i >> 5, r = i & 31;
    float v = (r < 31) ? weight[r * 64 + j] : 0.f;
    R2T[i] = v * v;
  }
  int nbase = blockIdx.x * 64;
  const float4* src = kg4 + (size_t)nbase * 16;
#pragma unroll
  for (int i = 0; i < 4; i++) {
    int idx = t + i * 256;
    float4 v = src[idx];               // may over-read past N into adjacent ws: safe
    float* dst = KG2 + (idx >> 4) * 68 + (idx & 15) * 4;
    dst[0] = v.x * v.x; dst[1] = v.y * v.y; dst[2] = v.z * v.z; dst[3] = v.w * v.w;
  }
  __syncthreads();
  int r = t & 31, ng = t >> 5;
  float acc[8] = {0.f, 0.f, 0.f, 0.f, 0.f, 0.f, 0.f, 0.f};
  const float* kbase = KG2 + ng * 8 * 68;
#pragma unroll 4
  for (int j4 = 0; j4 < 16; j4++) {
    float r0 = R2T[(j4 * 4 + 0) * 32 + r];
    float r1 = R2T[(j4 * 4 + 1) * 32 + r];
    float r2 = R2T[(j4 * 4 + 2) * 32 + r];
    float r3 = R2T[(j4 * 4 + 3) * 32 + r];
#pragma unroll
    for (int ni = 0; ni < 8; ni++) {
      float4 kv = *(const float4*)(kbase + ni * 68 + j4 * 4);
      acc[ni] = fmaf(kv.w, r3, fmaf(kv.z, r2, fmaf(kv.y, r1, fmaf(kv.x, r0, acc[ni]))));
    }
  }
  if (r < 31) {
    int nlim = N - nbase;
#pragma unroll
    for (int ni = 0; ni < 8; ni++) {
      int nl = ng * 8 + ni;
      if (nl < nlim) D[(size_t)(nbase + nl) * 32 + r] = acc[ni];
    }
  }
}

// ---------------- scatter-softmax + aggregation + normalize + residual ----------------
// pass 1: max only; pass 2: one exp/edge, unnormalized agg + sum; divide at end
__global__ __launch_bounds__(256) void k_aggnorm(const float* __restrict__ emb,
                          const float* __restrict__ D,
                          const int2* __restrict__ epack, const int* __restrict__ rowptr,
                          float* __restrict__ embn, float* __restrict__ out, int N) {
  __shared__ float wls[4 * CAP];
  __shared__ float DnL[4 * 32];
  int t = threadIdx.x, lane = t & 63, w = t >> 6, q = lane >> 4, s = lane & 15;
  int n = blockIdx.x * 4 + w;
  if (n >= N) return;
  int base = rowptr[n], deg = rowptr[n + 1] - base;
  float* wl = wls + w * CAP;
  float* Dn = DnL + w * 32;
  if (lane < 32) Dn[lane] = (lane < 31) ? D[(size_t)n * 32 + lane] : 0.f;
  float4 agg = make_float4(0.f, 0.f, 0.f, 0.f);
  float sacc = 0.f;
  float m = -1e30f;
  if (deg > 0) {
    // pass 1: segment max (lane-strided, no exp)
    for (int k = lane; k < deg; k += 64) {
      int2 p = epack[base + k];
      float wv = Dn[p.y] * D[(size_t)p.x * 32 + p.y];
      if (k < CAP) wl[k] = wv;
      m = fmaxf(m, wv);
    }
#pragma unroll
    for (int off = 32; off >= 1; off >>= 1) m = fmaxf(m, __shfl_xor(m, off, 64));
    // pass 2: quarter-parallel, prefetched
    bool valid = (q < deg);
    int kk = valid ? q : (deg - 1);
    int2 p = epack[base + kk];
    float4 e4 = *(const float4*)(emb + (size_t)p.x * 64 + s * 4);
    float wv = (kk < CAP) ? wl[kk] : Dn[p.y] * D[(size_t)p.x * 32 + p.y];
    for (int g0 = 0; g0 < deg; g0 += 4) {
      int2 pn = p; float4 e4n = e4; float wvn = wv; bool validn = false;
      if (g0 + 4 < deg) {
        int kn = g0 + 4 + q;
        validn = (kn < deg);
        int kkn = validn ? kn : (deg - 1);
        pn = epack[base + kkn];
        e4n = *(const float4*)(emb + (size_t)pn.x * 64 + s * 4);
        wvn = (kkn < CAP) ? wl[kkn] : Dn[pn.y] * D[(size_t)pn.x * 32 + pn.y];
      }
      float a = valid ? __expf(wv - m) : 0.f;
      sacc += a;
      agg.x = fmaf(a, e4.x, agg.x);
      agg.y = fmaf(a, e4.y, agg.y);
      agg.z = fmaf(a, e4.z, agg.z);
      agg.w = fmaf(a, e4.w, agg.w);
      p = pn; e4 = e4n; wv = wvn; valid = validn;
    }
  }
  REDQ(sacc)
  REDQ(agg.x) REDQ(agg.y) REDQ(agg.z) REDQ(agg.w)
  float sinv = 1.f / (sacc + 1e-16f);
  agg.x *= sinv; agg.y *= sinv; agg.z *= sinv; agg.w *= sinv;
  float ss = agg.x * agg.x + agg.y * agg.y + agg.z * agg.z + agg.w * agg.w;
  RED16(ss)
  float nr = fmaxf(sqrtf(ss), 1e-12f);
  float rin = 1.f / nr;
  float4 en;
  en.x = agg.x * rin; en.y = agg.y * rin; en.z = agg.z * rin; en.w = agg.w * rin;
  if (q == 0) {
    float4* eo = (float4*)(embn + (size_t)n * 64) + s;
    *eo = en;
    float4* oo = (float4*)(out + (size_t)n * 64) + s;
    float4 ov = *oo;
    ov.x += en.x; ov.y += en.y; ov.z += en.z; ov.w += en.w;
    *oo = ov;
  }
}

extern "C" void kernel_launch(void* const* d_in, const int* in_sizes, int n_in,
                              void* d_out, int out_size, void* d_ws, size_t ws_size,
                              hipStream_t stream) {
  const float* ent    = (const float*)d_in[0];
  const float* weight = (const float*)d_in[1];
  const float* Wq     = (const float*)d_in[2];
  const float* Wk     = (const float*)d_in[3];
  const float* Wv     = (const float*)d_in[4];
  const int*   eidx   = (const int*)d_in[5];
  const int*   etype  = (const int*)d_in[6];
  int N = in_sizes[0] / 64;
  int E = in_sizes[6];
  const int* head = eidx;
  const int* tail = eidx + E;
  int NC = (N + 1) / 2;

  float* ws   = (float*)d_ws;
  size_t o = 0;
  float* embA = ws + o; o += (size_t)N * 64;
  float* embB = ws + o; o += (size_t)N * 64;
  float* Gbuf = ws + o; o += (size_t)NC * 256;   // G (chunk), later D (N*32 <= NC*256)
  float* Mf   = ws + o; o += 64 * 256;
  int2* epack = (int2*)(ws + o); o += (size_t)E * 2;
  int* rowptr = (int*)(ws + o); o += N + 1;
  int* deg    = (int*)(ws + o); o += N;
  int* cur    = (int*)(ws + o); o += N;
  int* bsum   = (int*)(ws + o); o += 512;
  int* boff   = (int*)(ws + o); o += 512;
  float* Dbuf = Gbuf;

  int n4  = N * 64 / 4;
  int bl4 = (n4 + BD - 1) / BD;
  int ebl = (E + BD - 1) / BD;
  int nbl = (N + 3) / 4;
  int sbl = (N + BD - 1) / BD;

  k_init<<<bl4, BD, 0, stream>>>((const float4*)ent, (float4*)embA, (float4*)d_out, n4);

  hipMemsetAsync(deg, 0, (size_t)N * sizeof(int), stream);
  k_deg    <<<ebl, BD, 0, stream>>>(head, deg, E);
  k_scan_a <<<sbl, BD, 0, stream>>>(deg, rowptr, bsum, N);
  k_scan_b <<<1, 512, 0, stream>>>(bsum, boff, sbl);
  k_scan_c <<<sbl, BD, 0, stream>>>(rowptr, boff, N, E);
  k_curinit<<<sbl, BD, 0, stream>>>(rowptr, cur, N);
  k_scatter<<<ebl, BD, 0, stream>>>(head, tail, etype, cur, epack, E);

  float* emb = embA;
  float* alt = embB;
  for (int l = 0; l < 2; l++) {
    const float* wq = Wq + (size_t)l * 64 * 64;
    const float* wk = Wk + (size_t)l * 64 * 64;
    const float* wv = Wv + (size_t)l * 64 * 64;

    k_m<<<64, BD, 0, stream>>>(wq, wk, Mf);
    for (int c = 0; c < 2; c++) {
      int c0 = c * NC, c1 = (c0 + NC < N) ? c0 + NC : N;
      int cn = c1 - c0;
      k_g    <<<(cn + 63) / 64, BD, 0, stream>>>(emb, Mf, (float4*)Gbuf, c0, c1);
      k_fused<<<(cn + 3) / 4, BD, 0, stream>>>(emb, weight, (const float4*)Gbuf,
                                               wv, epack, rowptr, alt, c0, c1);
    }
    k_d<<<(N + 63) / 64, BD, 0, stream>>>((const float4*)alt, weight, Dbuf, N);
    k_aggnorm<<<nbl, BD, 0, stream>>>(emb, Dbuf, epack, rowptr,
                                      alt, (float*)d_out, N);
    float* tmp = emb; emb = alt; alt = tmp;
  }
}

// Round 7
// 686.935 us; speedup vs baseline: 17.0978x; 1.0649x over previous
//
#include <hip/hip_runtime.h>
#include <hip/hip_fp16.h>
#include <math.h>

#define BD 256
#define CAP 192
#define PBLK 2048

#define RED16(v) { v += __shfl_xor(v, 1, 64); v += __shfl_xor(v, 2, 64); \
                   v += __shfl_xor(v, 4, 64); v += __shfl_xor(v, 8, 64); }
#define REDQ(v)  { v += __shfl_xor(v, 16, 64); v += __shfl_xor(v, 32, 64); }

// ---------------- init: res = emb_cur = entity_emb; deg = 0 ----------------
__global__ void k_init(const float4* __restrict__ ent, float4* __restrict__ emb,
                       float4* __restrict__ out, int n4, int* __restrict__ deg, int N) {
  int i = blockIdx.x * BD + threadIdx.x;
  if (i < n4) { float4 v = ent[i]; emb[i] = v; out[i] = v; }
  if (i < N) deg[i] = 0;
}

// ---------------- CSR build ----------------
__global__ void k_deg(const int* __restrict__ head, int* __restrict__ deg, int E) {
  int e = blockIdx.x * BD + threadIdx.x;
  if (e < E) atomicAdd(&deg[head[e]], 1);
}

__global__ void k_scan_a(const int* __restrict__ deg, int* __restrict__ rowptr,
                         int* __restrict__ bsum, int N) {
  __shared__ int s[BD];
  int t = threadIdx.x, i = blockIdx.x * BD + t;
  int v = (i < N) ? deg[i] : 0;
  s[t] = v; __syncthreads();
  for (int off = 1; off < BD; off <<= 1) {
    int add = (t >= off) ? s[t - off] : 0;
    __syncthreads();
    s[t] += add;
    __syncthreads();
  }
  if (i < N) rowptr[i] = s[t] - v;
  if (t == BD - 1) bsum[blockIdx.x] = s[t];
}

__global__ void k_scan_b(const int* __restrict__ bsum, int* __restrict__ boff, int nb) {
  __shared__ int s[512];
  int t = threadIdx.x;
  int v = (t < nb) ? bsum[t] : 0;
  s[t] = v; __syncthreads();
  for (int off = 1; off < 512; off <<= 1) {
    int add = (t >= off) ? s[t - off] : 0;
    __syncthreads();
    s[t] += add;
    __syncthreads();
  }
  boff[t] = s[t] - v;
}

__global__ void k_scan_c(int* __restrict__ rowptr, int* __restrict__ cur,
                         const int* __restrict__ boff, int N, int E) {
  int i = blockIdx.x * BD + threadIdx.x;
  if (i < N) { int v = rowptr[i] + boff[blockIdx.x]; rowptr[i] = v; cur[i] = v; }
  if (i == 0) rowptr[N] = E;
}

__global__ void k_scatter(const int* __restrict__ head, const int* __restrict__ tail,
                          const int* __restrict__ etype,
                          int* __restrict__ cur, int2* __restrict__ epack, int E) {
  int e = blockIdx.x * BD + threadIdx.x;
  if (e < E) {
    int p = atomicAdd(&cur[head[e]], 1);
    epack[p] = make_int2(tail[e], etype[e] - 1);
  }
}

// ---------------- M_h = Wq_h @ Wk_h^T : Mf[m][i*4+h] ----------------
__global__ void k_m(const float* __restrict__ Wq, const float* __restrict__ Wk,
                    float* __restrict__ Mf) {
  int tid = blockIdx.x * BD + threadIdx.x;   // 0..16383
  int c = tid & 255;
  int m = tid >> 8;
  int i = c >> 2, h = c & 3;
  const float* wq = Wq + m * 64 + h * 16;
  const float* wk = Wk + i * 64 + h * 16;
  float acc = 0.f;
#pragma unroll
  for (int d = 0; d < 16; d++) acc = fmaf(wq[d], wk[d], acc);
  Mf[tid] = acc;
}

// ---------------- G = emb @ Mf  -> fp16  (LDS-tiled, 64 nodes/block) ----------------
__global__ __launch_bounds__(256) void k_g(const float* __restrict__ emb,
                                           const float* __restrict__ Mf,
                                           uint2* __restrict__ Gh2, int N) {
  __shared__ float lM[64 * 256];             // 64 KB
  int t = threadIdx.x;
  const float4* Mf4 = (const float4*)Mf;
  float4* lM4 = (float4*)lM;
  for (int i = t; i < 4096; i += BD) lM4[i] = Mf4[i];
  __syncthreads();
  int lane = t & 63, w = t >> 6;
  int nloc0 = blockIdx.x * 64 + w * 16;
#pragma unroll
  for (int b = 0; b < 2; b++) {
    int nl = nloc0 + b * 8;
    float4 acc[8];
#pragma unroll
    for (int ni = 0; ni < 8; ni++) acc[ni] = make_float4(0.f, 0.f, 0.f, 0.f);
#pragma unroll 8
    for (int m = 0; m < 64; m++) {
      float4 Mv = lM4[m * 64 + lane];
#pragma unroll
      for (int ni = 0; ni < 8; ni++) {
        float em = emb[(size_t)(nl + ni) * 64 + m];   // over-read past N stays in ws
        acc[ni].x = fmaf(em, Mv.x, acc[ni].x);
        acc[ni].y = fmaf(em, Mv.y, acc[ni].y);
        acc[ni].z = fmaf(em, Mv.z, acc[ni].z);
        acc[ni].w = fmaf(em, Mv.w, acc[ni].w);
      }
    }
#pragma unroll
    for (int ni = 0; ni < 8; ni++)
      if (nl + ni < N) {
        __half2 h01 = __floats2half2_rn(acc[ni].x, acc[ni].y);
        __half2 h23 = __floats2half2_rn(acc[ni].z, acc[ni].w);
        uint2 st;
        st.x = *(unsigned int*)&h01;
        st.y = *(unsigned int*)&h23;
        Gh2[(size_t)(nl + ni) * 64 + lane] = st;
      }
  }
}

// ---------------- fused: att + softmax-den + S + S@Wv -> kg  (persistent, quarter-parallel) ----------------
__global__ __launch_bounds__(256) void k_fused(const float* __restrict__ emb,
                        const float* __restrict__ weight,
                        const uint4* __restrict__ Ghq, const float4* __restrict__ Wv4,
                        const int2* __restrict__ epack, const int* __restrict__ rowptr,
                        float* __restrict__ kg, int N) {
  __shared__ float WvL[4096];                // 16 KB Wv staged (amortized over many nodes)
  __shared__ float SL[4 * 272];              // per-wave 4 segments of 68 (bank-skewed)
  int t = threadIdx.x, lane = t & 63, w = t >> 6, q = lane >> 4, s = lane & 15;
  {
    float4* W4 = (float4*)WvL;
    for (int i = t; i < 1024; i += BD) W4[i] = Wv4[i];
  }
  __syncthreads();
  float* L = SL + w * 272;
  int wid = blockIdx.x * 4 + w, nw = gridDim.x * 4;
  for (int n = wid; n < N; n += nw) {
    // G row (fp16): halves [s*16 .. s*16+16) -> two uint4 loads
    uint4 ga = Ghq[(size_t)n * 32 + s * 2];
    uint4 gb = Ghq[(size_t)n * 32 + s * 2 + 1];
    float2 ca = __half22float2(*(__half2*)&ga.x);
    float2 cb = __half22float2(*(__half2*)&ga.y);
    float4 G0 = make_float4(ca.x, ca.y, cb.x, cb.y);
    ca = __half22float2(*(__half2*)&ga.z);
    cb = __half22float2(*(__half2*)&ga.w);
    float4 G1 = make_float4(ca.x, ca.y, cb.x, cb.y);
    ca = __half22float2(*(__half2*)&gb.x);
    cb = __half22float2(*(__half2*)&gb.y);
    float4 G2 = make_float4(ca.x, ca.y, cb.x, cb.y);
    ca = __half22float2(*(__half2*)&gb.z);
    cb = __half22float2(*(__half2*)&gb.w);
    float4 G3 = make_float4(ca.x, ca.y, cb.x, cb.y);

    int base = rowptr[n], deg = rowptr[n + 1] - base;
    float4 den = make_float4(0.f, 0.f, 0.f, 0.f);
    float4 S0 = den, S1 = den, S2 = den, S3 = den;
    if (deg > 0) {
      bool valid = (q < deg);
      int kk = valid ? q : (deg - 1);
      int2 p = epack[base + kk];
      float4 e4 = *(const float4*)(emb + (size_t)p.x * 64 + s * 4);
      float4 r4 = *(const float4*)(weight + (size_t)p.y * 64 + s * 4);
      for (int g0 = 0; g0 < deg; g0 += 4) {
        int2 pn = p; float4 e4n = e4, r4n = r4; bool validn = false;
        if (g0 + 4 < deg) {
          int kn = g0 + 4 + q;
          validn = (kn < deg);
          int kkn = validn ? kn : (deg - 1);
          pn = epack[base + kkn];
          e4n = *(const float4*)(emb + (size_t)pn.x * 64 + s * 4);
          r4n = *(const float4*)(weight + (size_t)pn.y * 64 + s * 4);
        }
        float4 x;
        x.x = e4.x * r4.x; x.y = e4.y * r4.y; x.z = e4.z * r4.z; x.w = e4.w * r4.w;
        float4 a;
        a.x = fmaf(x.x, G0.x, fmaf(x.y, G1.x, fmaf(x.z, G2.x, x.w * G3.x)));
        a.y = fmaf(x.x, G0.y, fmaf(x.y, G1.y, fmaf(x.z, G2.y, x.w * G3.y)));
        a.z = fmaf(x.x, G0.z, fmaf(x.y, G1.z, fmaf(x.z, G2.z, x.w * G3.z)));
        a.w = fmaf(x.x, G0.w, fmaf(x.y, G1.w, fmaf(x.z, G2.w, x.w * G3.w)));
        RED16(a.x) RED16(a.y) RED16(a.z) RED16(a.w)
        a.x = fminf(10.f, fmaxf(-10.f, a.x));
        a.y = fminf(10.f, fmaxf(-10.f, a.y));
        a.z = fminf(10.f, fmaxf(-10.f, a.z));
        a.w = fminf(10.f, fmaxf(-10.f, a.w));
        float4 ev;
        ev.x = valid ? __expf(a.x) : 0.f;
        ev.y = valid ? __expf(a.y) : 0.f;
        ev.z = valid ? __expf(a.z) : 0.f;
        ev.w = valid ? __expf(a.w) : 0.f;
        den.x += ev.x; den.y += ev.y; den.z += ev.z; den.w += ev.w;
        S0.x = fmaf(ev.x, x.x, S0.x); S0.y = fmaf(ev.y, x.x, S0.y);
        S0.z = fmaf(ev.z, x.x, S0.z); S0.w = fmaf(ev.w, x.x, S0.w);
        S1.x = fmaf(ev.x, x.y, S1.x); S1.y = fmaf(ev.y, x.y, S1.y);
        S1.z = fmaf(ev.z, x.y, S1.z); S1.w = fmaf(ev.w, x.y, S1.w);
        S2.x = fmaf(ev.x, x.z, S2.x); S2.y = fmaf(ev.y, x.z, S2.y);
        S2.z = fmaf(ev.z, x.z, S2.z); S2.w = fmaf(ev.w, x.z, S2.w);
        S3.x = fmaf(ev.x, x.w, S3.x); S3.y = fmaf(ev.y, x.w, S3.y);
        S3.z = fmaf(ev.z, x.w, S3.z); S3.w = fmaf(ev.w, x.w, S3.w);
        p = pn; e4 = e4n; r4 = r4n; valid = validn;
      }
    }
    REDQ(den.x) REDQ(den.y) REDQ(den.z) REDQ(den.w)
    REDQ(S0.x) REDQ(S0.y) REDQ(S0.z) REDQ(S0.w)
    REDQ(S1.x) REDQ(S1.y) REDQ(S1.z) REDQ(S1.w)
    REDQ(S2.x) REDQ(S2.y) REDQ(S2.z) REDQ(S2.w)
    REDQ(S3.x) REDQ(S3.y) REDQ(S3.z) REDQ(S3.w)
    float4 inv;
    inv.x = 1.f / (den.x + 1e-8f); inv.y = 1.f / (den.y + 1e-8f);
    inv.z = 1.f / (den.z + 1e-8f); inv.w = 1.f / (den.w + 1e-8f);
    S0.x *= inv.x; S0.y *= inv.y; S0.z *= inv.z; S0.w *= inv.w;
    S1.x *= inv.x; S1.y *= inv.y; S1.z *= inv.z; S1.w *= inv.w;
    S2.x *= inv.x; S2.y *= inv.y; S2.z *= inv.z; S2.w *= inv.w;
    S3.x *= inv.x; S3.y *= inv.y; S3.z *= inv.z; S3.w *= inv.w;
    if (q == 0) {
      *(float4*)(L +       s * 4) = make_float4(S0.x, S1.x, S2.x, S3.x);
      *(float4*)(L +  68 + s * 4) = make_float4(S0.y, S1.y, S2.y, S3.y);
      *(float4*)(L + 136 + s * 4) = make_float4(S0.z, S1.z, S2.z, S3.z);
      *(float4*)(L + 204 + s * 4) = make_float4(S0.w, S1.w, S2.w, S3.w);
    }
    const float4* L4 = (const float4*)(L + q * 68);
    float acc = 0.f;
#pragma unroll
    for (int i4 = 0; i4 < 16; i4++) {
      float4 Lv = L4[i4];
      acc = fmaf(Lv.x, WvL[(i4 * 4 + 0) * 64 + lane], acc);
      acc = fmaf(Lv.y, WvL[(i4 * 4 + 1) * 64 + lane], acc);
      acc = fmaf(Lv.z, WvL[(i4 * 4 + 2) * 64 + lane], acc);
      acc = fmaf(Lv.w, WvL[(i4 * 4 + 3) * 64 + lane], acc);
    }
    kg[(size_t)n * 64 + lane] = acc;
  }
}

// ---------------- D = KG^2 @ REL^2T  (64 nodes/block, LDS-staged) ----------------
__global__ __launch_bounds__(256) void k_d(const float4* __restrict__ kg4,
                    const float* __restrict__ weight,
                    float* __restrict__ D, int N) {
  __shared__ float R2T[64 * 32];       // [j][r] = weight[r][j]^2
  __shared__ float KG2[64 * 68];       // [node][j] padded
  int t = threadIdx.x;
  for (int i = t; i < 2048; i += BD) {
    int j = i >> 5, r = i & 31;
    float v = (r < 31) ? weight[r * 64 + j] : 0.f;
    R2T[i] = v * v;
  }
  int nbase = blockIdx.x * 64;
  const float4* src = kg4 + (size_t)nbase * 16;
#pragma unroll
  for (int i = 0; i < 4; i++) {
    int idx = t + i * 256;
    float4 v = src[idx];               // may over-read past N into adjacent ws: safe
    float* dst = KG2 + (idx >> 4) * 68 + (idx & 15) * 4;
    dst[0] = v.x * v.x; dst[1] = v.y * v.y; dst[2] = v.z * v.z; dst[3] = v.w * v.w;
  }
  __syncthreads();
  int r = t & 31, ng = t >> 5;
  float acc[8] = {0.f, 0.f, 0.f, 0.f, 0.f, 0.f, 0.f, 0.f};
  const float* kbase = KG2 + ng * 8 * 68;
#pragma unroll 4
  for (int j4 = 0; j4 < 16; j4++) {
    float r0 = R2T[(j4 * 4 + 0) * 32 + r];
    float r1 = R2T[(j4 * 4 + 1) * 32 + r];
    float r2 = R2T[(j4 * 4 + 2) * 32 + r];
    float r3 = R2T[(j4 * 4 + 3) * 32 + r];
#pragma unroll
    for (int ni = 0; ni < 8; ni++) {
      float4 kv = *(const float4*)(kbase + ni * 68 + j4 * 4);
      acc[ni] = fmaf(kv.w, r3, fmaf(kv.z, r2, fmaf(kv.y, r1, fmaf(kv.x, r0, acc[ni]))));
    }
  }
  if (r < 31) {
    int nlim = N - nbase;
#pragma unroll
    for (int ni = 0; ni < 8; ni++) {
      int nl = ng * 8 + ni;
      if (nl < nlim) D[(size_t)(nbase + nl) * 32 + r] = acc[ni];
    }
  }
}

// ---------------- scatter-softmax + aggregation + normalize + residual (persistent) ----------------
__global__ __launch_bounds__(256) void k_aggnorm(const float* __restrict__ emb,
                          const float* __restrict__ D,
                          const int2* __restrict__ epack, const int* __restrict__ rowptr,
                          float* __restrict__ embn, float* __restrict__ out, int N) {
  __shared__ float wls[4 * CAP];
  __shared__ float DnL[4 * 32];
  int t = threadIdx.x, lane = t & 63, w = t >> 6, q = lane >> 4, s = lane & 15;
  float* wl = wls + w * CAP;
  float* Dn = DnL + w * 32;
  int wid = blockIdx.x * 4 + w, nw = gridDim.x * 4;
  for (int n = wid; n < N; n += nw) {
    int base = rowptr[n], deg = rowptr[n + 1] - base;
    if (lane < 32) Dn[lane] = (lane < 31) ? D[(size_t)n * 32 + lane] : 0.f;
    float4 agg = make_float4(0.f, 0.f, 0.f, 0.f);
    float sacc = 0.f;
    float m = -1e30f;
    if (deg > 0) {
      for (int k = lane; k < deg; k += 64) {
        int2 p = epack[base + k];
        float wv = Dn[p.y] * D[(size_t)p.x * 32 + p.y];
        if (k < CAP) wl[k] = wv;
        m = fmaxf(m, wv);
      }
#pragma unroll
      for (int off = 32; off >= 1; off >>= 1) m = fmaxf(m, __shfl_xor(m, off, 64));
      bool valid = (q < deg);
      int kk = valid ? q : (deg - 1);
      int2 p = epack[base + kk];
      float4 e4 = *(const float4*)(emb + (size_t)p.x * 64 + s * 4);
      float wv = (kk < CAP) ? wl[kk] : Dn[p.y] * D[(size_t)p.x * 32 + p.y];
      for (int g0 = 0; g0 < deg; g0 += 4) {
        int2 pn = p; float4 e4n = e4; float wvn = wv; bool validn = false;
        if (g0 + 4 < deg) {
          int kn = g0 + 4 + q;
          validn = (kn < deg);
          int kkn = validn ? kn : (deg - 1);
          pn = epack[base + kkn];
          e4n = *(const float4*)(emb + (size_t)pn.x * 64 + s * 4);
          wvn = (kkn < CAP) ? wl[kkn] : Dn[pn.y] * D[(size_t)pn.x * 32 + pn.y];
        }
        float a = valid ? __expf(wv - m) : 0.f;
        sacc += a;
        agg.x = fmaf(a, e4.x, agg.x);
        agg.y = fmaf(a, e4.y, agg.y);
        agg.z = fmaf(a, e4.z, agg.z);
        agg.w = fmaf(a, e4.w, agg.w);
        p = pn; e4 = e4n; wv = wvn; valid = validn;
      }
    }
    REDQ(sacc)
    REDQ(agg.x) REDQ(agg.y) REDQ(agg.z) REDQ(agg.w)
    float sinv = 1.f / (sacc + 1e-16f);
    agg.x *= sinv; agg.y *= sinv; agg.z *= sinv; agg.w *= sinv;
    float ss = agg.x * agg.x + agg.y * agg.y + agg.z * agg.z + agg.w * agg.w;
    RED16(ss)
    float nr = fmaxf(sqrtf(ss), 1e-12f);
    float rin = 1.f / nr;
    float4 en;
    en.x = agg.x * rin; en.y = agg.y * rin; en.z = agg.z * rin; en.w = agg.w * rin;
    if (q == 0) {
      float4* eo = (float4*)(embn + (size_t)n * 64) + s;
      *eo = en;
      float4* oo = (float4*)(out + (size_t)n * 64) + s;
      float4 ov = *oo;
      ov.x += en.x; ov.y += en.y; ov.z += en.z; ov.w += en.w;
      *oo = ov;
    }
  }
}

extern "C" void kernel_launch(void* const* d_in, const int* in_sizes, int n_in,
                              void* d_out, int out_size, void* d_ws, size_t ws_size,
                              hipStream_t stream) {
  const float* ent    = (const float*)d_in[0];
  const float* weight = (const float*)d_in[1];
  const float* Wq     = (const float*)d_in[2];
  const float* Wk     = (const float*)d_in[3];
  const float* Wv     = (const float*)d_in[4];
  const int*   eidx   = (const int*)d_in[5];
  const int*   etype  = (const int*)d_in[6];
  int N = in_sizes[0] / 64;
  int E = in_sizes[6];
  const int* head = eidx;
  const int* tail = eidx + E;

  // workspace layout (float units)
  float* ws   = (float*)d_ws;
  size_t o = 0;
  float* embA = ws + o; o += (size_t)N * 64;
  float* embB = ws + o; o += (size_t)N * 64;
  float* Gbuf = ws + o; o += (size_t)N * 128;    // fp16 G (N*256 halves); reused as D (N*32 f32)
  float* Mf   = ws + o; o += 64 * 256;
  int2* epack = (int2*)(ws + o); o += (size_t)E * 2;
  int* rowptr = (int*)(ws + o); o += N + 1;
  int* deg    = (int*)(ws + o); o += N;
  int* cur    = (int*)(ws + o); o += N;
  int* bsum   = (int*)(ws + o); o += 512;
  int* boff   = (int*)(ws + o); o += 512;
  float* Dbuf = Gbuf;

  int n4  = N * 64 / 4;
  int bl4 = (n4 + BD - 1) / BD;
  int ebl = (E + BD - 1) / BD;
  int sbl = (N + BD - 1) / BD;

  k_init<<<bl4, BD, 0, stream>>>((const float4*)ent, (float4*)embA, (float4*)d_out,
                                 n4, deg, N);
  k_deg    <<<ebl, BD, 0, stream>>>(head, deg, E);
  k_scan_a <<<sbl, BD, 0, stream>>>(deg, rowptr, bsum, N);
  k_scan_b <<<1, 512, 0, stream>>>(bsum, boff, sbl);
  k_scan_c <<<sbl, BD, 0, stream>>>(rowptr, cur, boff, N, E);
  k_scatter<<<ebl, BD, 0, stream>>>(head, tail, etype, cur, epack, E);

  float* emb = embA;
  float* alt = embB;
  for (int l = 0; l < 2; l++) {
    const float* wq = Wq + (size_t)l * 64 * 64;
    const float* wk = Wk + (size_t)l * 64 * 64;
    const float* wv = Wv + (size_t)l * 64 * 64;

    k_m<<<64, BD, 0, stream>>>(wq, wk, Mf);
    k_g<<<(N + 63) / 64, BD, 0, stream>>>(emb, Mf, (uint2*)Gbuf, N);
    k_fused<<<PBLK, BD, 0, stream>>>(emb, weight, (const uint4*)Gbuf,
                                     (const float4*)wv, epack, rowptr, alt, N);
    k_d<<<(N + 63) / 64, BD, 0, stream>>>((const float4*)alt, weight, Dbuf, N);
    k_aggnorm<<<PBLK, BD, 0, stream>>>(emb, Dbuf, epack, rowptr,
                                       alt, (float*)d_out, N);
    float* tmp = emb; emb = alt; alt = tmp;
  }
}